// Round 1
// baseline (1904.059 us; speedup 1.0000x reference)
//
#include <hip/hip_runtime.h>
#include <hip/hip_bf16.h>
#include <cstddef>
#include <cstdint>

// Problem constants
#define BB   2
#define NN   8192
#define CA   128
#define CS   384
#define CZ   16
#define HH   4
#define DD   32
#define NQW  32      // NQ
#define NKW  128     // NK
#define NBLK 3
#define WW   256     // N / NQ
#define MR   (BB*NN) // 16384 rows
#define HIDN 256     // 2*CA

__device__ __forceinline__ float sigmoidf_(float x) { return 1.f / (1.f + expf(-x)); }

// ---------------------------------------------------------------------------
// LayerNorm of s (C_S = 384), one wave per row.
// ---------------------------------------------------------------------------
__global__ __launch_bounds__(256) void ln_s_kernel(const float* __restrict__ s,
                                                   float* __restrict__ s_ln) {
  int row  = blockIdx.x * 4 + (threadIdx.x >> 6);
  int lane = threadIdx.x & 63;
  const float* sr = s + (size_t)row * CS;
  float x[6];
  float sum = 0.f, sq = 0.f;
#pragma unroll
  for (int t = 0; t < 6; ++t) { x[t] = sr[lane + 64*t]; sum += x[t]; sq += x[t]*x[t]; }
#pragma unroll
  for (int off = 32; off; off >>= 1) { sum += __shfl_down(sum, off); sq += __shfl_down(sq, off); }
  sum = __shfl(sum, 0); sq = __shfl(sq, 0);
  float mean = sum * (1.f/CS);
  float var  = sq  * (1.f/CS) - mean*mean;
  float rstd = rsqrtf(var + 1e-5f);
  float* orow = s_ln + (size_t)row * CS;
#pragma unroll
  for (int t = 0; t < 6; ++t) orow[lane + 64*t] = (x[t]-mean)*rstd;
}

// ---------------------------------------------------------------------------
// LN(a) + adaLN modulation for both attention (amod) and transition (tmod).
// One wave per row of 128.
// ---------------------------------------------------------------------------
__global__ __launch_bounds__(256) void modln_kernel(const float* __restrict__ a,
                                                    const float* __restrict__ sp0,
                                                    const float* __restrict__ sp1,
                                                    const float* __restrict__ sp3,
                                                    const float* __restrict__ sp4,
                                                    float* __restrict__ amod,
                                                    float* __restrict__ tmod) {
  int row  = blockIdx.x * 4 + (threadIdx.x >> 6);
  int lane = threadIdx.x & 63;
  const float* ar = a + (size_t)row * CA;
  float x0 = ar[lane], x1 = ar[lane + 64];
  float sum = x0 + x1, sq = x0*x0 + x1*x1;
#pragma unroll
  for (int off = 32; off; off >>= 1) { sum += __shfl_down(sum, off); sq += __shfl_down(sq, off); }
  sum = __shfl(sum, 0); sq = __shfl(sq, 0);
  float mean = sum * (1.f/CA);
  float var  = sq  * (1.f/CA) - mean*mean;
  float rstd = rsqrtf(var + 1e-5f);
  float n0 = (x0-mean)*rstd, n1 = (x1-mean)*rstd;
  size_t i0 = (size_t)row * CA + lane;
  amod[i0]      = sp0[i0]     *n0 + sp1[i0];
  amod[i0 + 64] = sp0[i0 + 64]*n1 + sp1[i0 + 64];
  tmod[i0]      = sp3[i0]     *n0 + sp4[i0];
  tmod[i0 + 64] = sp3[i0 + 64]*n1 + sp4[i0 + 64];
}

// ---------------------------------------------------------------------------
// Generic tiled fp32 GEMM, 64x64 block tile, BK=16, 256 threads, 4x4/thread.
// Multiple "jobs" (different B matrices / epilogues) share A via blockIdx.z.
// modes: 0 = +bias, 1 = sigmoid(+bias), 2 = *gate, 3 = *gate + out (accum),
//        4 = silu(A@B) * (A@B2)
// ---------------------------------------------------------------------------
struct GemmJob {
  const float* Bmat;
  const float* Bmat2;
  const float* bias;
  const float* gate;
  float* out;
  int mode;
  int pad;
};
struct GemmJobs { GemmJob j[6]; };

__global__ __launch_bounds__(256) void gemm_multi(const float* __restrict__ A,
                                                  int K, int Nn, GemmJobs jobs) {
  GemmJob jb = jobs.j[blockIdx.z];
  const int bm = blockIdx.y * 64, bn = blockIdx.x * 64;
  __shared__ float As[16][65];
  __shared__ float Bs[16][68];
  __shared__ float Bs2[16][68];
  float acc[4][4] = {};
  float acc2[4][4] = {};
  const int tid = threadIdx.x;
  const int tx = tid & 15, ty = tid >> 4;
  const bool dual = (jb.mode == 4);
  const int ar = tid >> 2, ac = (tid & 3) * 4;
  const int br = tid >> 4, bc = (tid & 15) * 4;

  for (int k0 = 0; k0 < K; k0 += 16) {
    float4 av = *(const float4*)(A + (size_t)(bm + ar) * K + k0 + ac);
    As[ac+0][ar] = av.x; As[ac+1][ar] = av.y; As[ac+2][ar] = av.z; As[ac+3][ar] = av.w;
    float4 bv = *(const float4*)(jb.Bmat + (size_t)(k0 + br) * Nn + bn + bc);
    *(float4*)&Bs[br][bc] = bv;
    if (dual) {
      float4 bv2 = *(const float4*)(jb.Bmat2 + (size_t)(k0 + br) * Nn + bn + bc);
      *(float4*)&Bs2[br][bc] = bv2;
    }
    __syncthreads();
#pragma unroll
    for (int kk = 0; kk < 16; ++kk) {
      float a[4], b[4];
#pragma unroll
      for (int i2 = 0; i2 < 4; ++i2) a[i2] = As[kk][ty*4+i2];
#pragma unroll
      for (int j2 = 0; j2 < 4; ++j2) b[j2] = Bs[kk][tx*4+j2];
#pragma unroll
      for (int i2 = 0; i2 < 4; ++i2)
#pragma unroll
        for (int j2 = 0; j2 < 4; ++j2) acc[i2][j2] = fmaf(a[i2], b[j2], acc[i2][j2]);
      if (dual) {
        float b2[4];
#pragma unroll
        for (int j2 = 0; j2 < 4; ++j2) b2[j2] = Bs2[kk][tx*4+j2];
#pragma unroll
        for (int i2 = 0; i2 < 4; ++i2)
#pragma unroll
          for (int j2 = 0; j2 < 4; ++j2) acc2[i2][j2] = fmaf(a[i2], b2[j2], acc2[i2][j2]);
      }
    }
    __syncthreads();
  }

#pragma unroll
  for (int i2 = 0; i2 < 4; ++i2) {
    int m = bm + ty*4 + i2;
#pragma unroll
    for (int j2 = 0; j2 < 4; ++j2) {
      int n = bn + tx*4 + j2;
      size_t idx = (size_t)m * Nn + n;
      float v = acc[i2][j2];
      switch (jb.mode) {
        case 0: if (jb.bias) v += jb.bias[n]; break;
        case 1: v = sigmoidf_(v + (jb.bias ? jb.bias[n] : 0.f)); break;
        case 2: v = v * jb.gate[idx]; break;
        case 3: v = v * jb.gate[idx] + jb.out[idx]; break;
        case 4: { float xx = v; v = (xx * sigmoidf_(xx)) * acc2[i2][j2]; } break;
      }
      jb.out[idx] = v;
    }
  }
}

// ---------------------------------------------------------------------------
// Pair bias: bias[b,w,q,k,h] = LN16(p[b,w,q,k,:]) @ (lnz_w*wb) + lnz_b@wb
// One thread per (b,w,q,k) tuple.
// ---------------------------------------------------------------------------
__global__ __launch_bounds__(256) void bias_kernel(const float* __restrict__ p,
                                                   const float* __restrict__ lnz_w,
                                                   const float* __restrict__ lnz_b,
                                                   const float* __restrict__ wb,
                                                   float* __restrict__ biasb) {
  __shared__ float effW[16][4];
  __shared__ float effb[4];
  int tid = threadIdx.x;
  if (tid < 64) effW[tid >> 2][tid & 3] = lnz_w[tid >> 2] * wb[tid];
  if (tid < 4) {
    float acc = 0.f;
    for (int z = 0; z < 16; ++z) acc += lnz_b[z] * wb[z*4 + tid];
    effb[tid] = acc;
  }
  __syncthreads();
  size_t t = (size_t)blockIdx.x * 256 + tid;
  const float4* pr = (const float4*)(p + t * 16);
  float4 p0 = pr[0], p1 = pr[1], p2 = pr[2], p3 = pr[3];
  float x[16] = {p0.x,p0.y,p0.z,p0.w, p1.x,p1.y,p1.z,p1.w,
                 p2.x,p2.y,p2.z,p2.w, p3.x,p3.y,p3.z,p3.w};
  float sum = 0.f, sq = 0.f;
#pragma unroll
  for (int z = 0; z < 16; ++z) { sum += x[z]; sq += x[z]*x[z]; }
  float mean = sum * (1.f/16.f);
  float var  = sq  * (1.f/16.f) - mean*mean;
  float rstd = rsqrtf(var + 1e-5f);
  float o[4];
#pragma unroll
  for (int hh = 0; hh < 4; ++hh) {
    float acc = effb[hh];
#pragma unroll
    for (int z = 0; z < 16; ++z) acc += (x[z]-mean)*rstd * effW[z][hh];
    o[hh] = acc;
  }
  *(float4*)(biasb + t*4) = make_float4(o[0], o[1], o[2], o[3]);
}

// ---------------------------------------------------------------------------
// Windowed attention: one block per (b, w, h). 32 queries x 128 keys x 32 dim.
// Writes g-gated output.
// ---------------------------------------------------------------------------
__global__ __launch_bounds__(256) void attn_kernel(const float* __restrict__ Qb,
                                                   const float* __restrict__ Kb,
                                                   const float* __restrict__ Vb,
                                                   const float* __restrict__ Gb,
                                                   const float* __restrict__ biasb,
                                                   float* __restrict__ Ob) {
  const int w = blockIdx.x, h = blockIdx.y, b = blockIdx.z;
  __shared__ float Qs[32][33];
  __shared__ float Ks[128][33];
  __shared__ float Vs[128][33];
  __shared__ float Ls[32][132];
  __shared__ float redm[32][8];
  __shared__ float reds[32][8];
  const int tid = threadIdx.x;

  { // load Q tile (1024 floats)
    int qq = tid >> 3, dg = (tid & 7) * 4;
    float4 v = *(const float4*)(Qb + (size_t)(b*NN + w*NQW + qq) * CA + h*DD + dg);
    Qs[qq][dg] = v.x; Qs[qq][dg+1] = v.y; Qs[qq][dg+2] = v.z; Qs[qq][dg+3] = v.w;
  }
#pragma unroll
  for (int ii = 0; ii < 4; ++ii) { // load K,V tiles (4096 floats each)
    int f = tid + 256*ii;
    int j = f >> 3, dg = (f & 7) * 4;
    int r = w*NQW - 48 + j;
    float4 kv = {0,0,0,0}, vv = {0,0,0,0};
    if (r >= 0 && r < NN) {
      size_t base = (size_t)(b*NN + r) * CA + h*DD + dg;
      kv = *(const float4*)(Kb + base);
      vv = *(const float4*)(Vb + base);
    }
    Ks[j][dg]=kv.x; Ks[j][dg+1]=kv.y; Ks[j][dg+2]=kv.z; Ks[j][dg+3]=kv.w;
    Vs[j][dg]=vv.x; Vs[j][dg+1]=vv.y; Vs[j][dg+2]=vv.z; Vs[j][dg+3]=vv.w;
  }
  __syncthreads();

  const int qq = tid >> 3, sub = tid & 7;
  const float invd = 0.17677669529663687f; // 1/sqrt(32)
  const float* brow = biasb + (size_t)((b*WW + w)*NQW + qq) * (NKW*HH) + h;
  float lmax = -3.4e38f;
#pragma unroll
  for (int jj = 0; jj < 16; ++jj) {
    int j = sub + jj*8;
    float acc = 0.f;
#pragma unroll
    for (int d = 0; d < 32; ++d) acc = fmaf(Qs[qq][d], Ks[j][d], acc);
    int r = w*NQW - 48 + j;
    float l = (r >= 0 && r < NN) ? acc * invd + brow[(size_t)j*HH] : -1e9f;
    Ls[qq][j] = l;
    lmax = fmaxf(lmax, l);
  }
  redm[qq][sub] = lmax;
  __syncthreads();
  float m = redm[qq][0];
#pragma unroll
  for (int t2 = 1; t2 < 8; ++t2) m = fmaxf(m, redm[qq][t2]);
  float lsum = 0.f;
#pragma unroll
  for (int jj = 0; jj < 16; ++jj) {
    int j = sub + jj*8;
    float e = expf(Ls[qq][j] - m);
    Ls[qq][j] = e;
    lsum += e;
  }
  reds[qq][sub] = lsum;
  __syncthreads();
  float ssum = 0.f;
#pragma unroll
  for (int t2 = 0; t2 < 8; ++t2) ssum += reds[qq][t2];
  float invs = 1.f / ssum;

  const int dg = sub * 4;
  float acc[4] = {0.f, 0.f, 0.f, 0.f};
  for (int j = 0; j < 128; ++j) {
    float pv = Ls[qq][j];
#pragma unroll
    for (int dd = 0; dd < 4; ++dd) acc[dd] = fmaf(pv, Vs[j][dg+dd], acc[dd]);
  }
  size_t obase = (size_t)(b*NN + w*NQW + qq) * CA + h*DD + dg;
  float4 gv = *(const float4*)(Gb + obase);
  float4 ov;
  ov.x = gv.x * acc[0] * invs;
  ov.y = gv.y * acc[1] * invs;
  ov.z = gv.z * acc[2] * invs;
  ov.w = gv.w * acc[3] * invs;
  *(float4*)(Ob + obase) = ov;
}

// ---------------------------------------------------------------------------
// Host-side orchestration.  Workspace need: ~50.4M floats = ~202 MB.
// ---------------------------------------------------------------------------
extern "C" void kernel_launch(void* const* d_in, const int* in_sizes, int n_in,
                              void* d_out, int out_size, void* d_ws, size_t ws_size,
                              hipStream_t stream) {
  const float* q             = (const float*)d_in[0];
  const float* s             = (const float*)d_in[1];
  const float* p             = (const float*)d_in[2];
  const float* adaln_scale_w = (const float*)d_in[3];
  const float* adaln_scale_b = (const float*)d_in[4];
  const float* adaln_shift_w = (const float*)d_in[5];
  const float* wq            = (const float*)d_in[6];
  const float* bq            = (const float*)d_in[7];
  const float* wk            = (const float*)d_in[8];
  const float* wv            = (const float*)d_in[9];
  const float* lnz_w         = (const float*)d_in[10];
  const float* lnz_b         = (const float*)d_in[11];
  const float* wb_pair       = (const float*)d_in[12];
  const float* wg            = (const float*)d_in[13];
  const float* wo            = (const float*)d_in[14];
  const float* sgate_w       = (const float*)d_in[15];
  const float* sgate_b       = (const float*)d_in[16];
  const float* t_scale_w     = (const float*)d_in[17];
  const float* t_scale_b     = (const float*)d_in[18];
  const float* t_shift_w     = (const float*)d_in[19];
  const float* t_wa          = (const float*)d_in[20];
  const float* t_wb          = (const float*)d_in[21];
  const float* t_wo          = (const float*)d_in[22];
  const float* t_sgate_w     = (const float*)d_in[23];
  const float* t_sgate_b     = (const float*)d_in[24];
  float* out = (float*)d_out;
  float* ws  = (float*)d_ws;

  const size_t MC = (size_t)MR * CA; // 2097152
  float* s_ln  = ws;                          // MR*CS
  float* SP    = s_ln + (size_t)MR * CS;      // 6 * MC
  float* amod  = SP + 6*MC;
  float* tmod  = amod + MC;
  float* Qb    = tmod + MC;
  float* Kb    = Qb + MC;
  float* Vb    = Kb + MC;
  float* Gb    = Vb + MC;
  float* Ob    = Gb + MC;
  float* HIDb  = Ob + MC;                     // MR*HIDN = 2*MC
  float* biasb = HIDb + (size_t)MR * HIDN;    // B*W*NQ*NK*H = 4*MC
  float* abuf0 = biasb + (size_t)BB*WW*NQW*NKW*HH;
  float* abuf1 = abuf0 + MC;

  ln_s_kernel<<<MR/4, 256, 0, stream>>>(s, s_ln);

  for (int i = 0; i < NBLK; ++i) {
    const float* a_in = (i == 0) ? q : (i == 1 ? abuf0 : abuf1);
    float* a_out = (i == 2) ? out : (i == 0 ? abuf0 : abuf1);

    // 6 projections of s_ln (K=384 -> N=128 each)
    GemmJobs js = {};
    js.j[0] = GemmJob{adaln_scale_w + (size_t)i*CS*CA, nullptr, adaln_scale_b + i*CA, nullptr, SP + 0*MC, 1, 0};
    js.j[1] = GemmJob{adaln_shift_w + (size_t)i*CS*CA, nullptr, nullptr,              nullptr, SP + 1*MC, 0, 0};
    js.j[2] = GemmJob{sgate_w       + (size_t)i*CS*CA, nullptr, sgate_b   + i*CA,     nullptr, SP + 2*MC, 1, 0};
    js.j[3] = GemmJob{t_scale_w     + (size_t)i*CS*CA, nullptr, t_scale_b + i*CA,     nullptr, SP + 3*MC, 1, 0};
    js.j[4] = GemmJob{t_shift_w     + (size_t)i*CS*CA, nullptr, nullptr,              nullptr, SP + 4*MC, 0, 0};
    js.j[5] = GemmJob{t_sgate_w     + (size_t)i*CS*CA, nullptr, t_sgate_b + i*CA,     nullptr, SP + 5*MC, 1, 0};
    gemm_multi<<<dim3(CA/64, MR/64, 6), 256, 0, stream>>>(s_ln, CS, CA, js);

    // LN(a) + both modulations
    modln_kernel<<<MR/4, 256, 0, stream>>>(a_in, SP + 0*MC, SP + 1*MC, SP + 3*MC, SP + 4*MC, amod, tmod);

    // Q, K, V, G projections (K=128 -> N=128 each)
    GemmJobs jq = {};
    jq.j[0] = GemmJob{wq + (size_t)i*CA*CA, nullptr, bq + i*CA, nullptr, Qb, 0, 0};
    jq.j[1] = GemmJob{wk + (size_t)i*CA*CA, nullptr, nullptr,   nullptr, Kb, 0, 0};
    jq.j[2] = GemmJob{wv + (size_t)i*CA*CA, nullptr, nullptr,   nullptr, Vb, 0, 0};
    jq.j[3] = GemmJob{wg + (size_t)i*CA*CA, nullptr, nullptr,   nullptr, Gb, 1, 0};
    gemm_multi<<<dim3(CA/64, MR/64, 4), 256, 0, stream>>>(amod, CA, CA, jq);

    // pair bias from p
    bias_kernel<<<(BB*WW*NQW*NKW)/256, 256, 0, stream>>>(
        p, lnz_w + i*CZ, lnz_b + i*CZ, wb_pair + (size_t)i*CZ*HH, biasb);

    // windowed attention (writes g-gated output)
    attn_kernel<<<dim3(WW, HH, BB), 256, 0, stream>>>(Qb, Kb, Vb, Gb, biasb, Ob);

    // attn_out = (O @ wo) * sgate  -> a_out
    GemmJobs ja = {};
    ja.j[0] = GemmJob{wo + (size_t)i*CA*CA, nullptr, nullptr, SP + 2*MC, a_out, 2, 0};
    gemm_multi<<<dim3(CA/64, MR/64, 1), 256, 0, stream>>>(Ob, CA, CA, ja);

    // hidden = silu(tmod @ t_wa) * (tmod @ t_wb)   (K=128 -> N=256)
    GemmJobs jh = {};
    jh.j[0] = GemmJob{t_wa + (size_t)i*CA*HIDN, t_wb + (size_t)i*CA*HIDN, nullptr, nullptr, HIDb, 4, 0};
    gemm_multi<<<dim3(HIDN/64, MR/64, 1), 256, 0, stream>>>(tmod, CA, HIDN, jh);

    // a_out += (hidden @ t_wo) * t_sgate   (K=256 -> N=128)
    GemmJobs jt = {};
    jt.j[0] = GemmJob{t_wo + (size_t)i*HIDN*CA, nullptr, nullptr, SP + 5*MC, a_out, 3, 0};
    gemm_multi<<<dim3(CA/64, MR/64, 1), 256, 0, stream>>>(HIDb, HIDN, CA, jt);
  }
}

// Round 2
// 860.195 us; speedup vs baseline: 2.2135x; 2.2135x over previous
//
#include <hip/hip_runtime.h>
#include <hip/hip_bf16.h>
#include <cstddef>
#include <cstdint>

// Problem constants
#define BB   2
#define NN   8192
#define CA   128
#define CS   384
#define CZ   16
#define HH   4
#define DD   32
#define NQW  32      // NQ
#define NKW  128     // NK
#define NBLK 3
#define WW   256     // N / NQ
#define MR   (BB*NN) // 16384 rows
#define HIDN 256     // 2*CA

typedef __attribute__((ext_vector_type(8))) short short8;
typedef __attribute__((ext_vector_type(4))) float floatx4;

__device__ __forceinline__ float sigmoidf_(float x) { return 1.f / (1.f + expf(-x)); }

__device__ __forceinline__ unsigned short f2bf(float x) {
  unsigned u = __float_as_uint(x);
  unsigned r = (u + 0x7fffu + ((u >> 16) & 1u)) >> 16;
  return (unsigned short)r;
}

// ---------------------------------------------------------------------------
// LayerNorm of s (C_S = 384), one wave per row -> bf16 out.
// ---------------------------------------------------------------------------
__global__ __launch_bounds__(256) void ln_s_kernel(const float* __restrict__ s,
                                                   unsigned short* __restrict__ s_ln_bf) {
  int row  = blockIdx.x * 4 + (threadIdx.x >> 6);
  int lane = threadIdx.x & 63;
  const float* sr = s + (size_t)row * CS;
  float x[6];
  float sum = 0.f, sq = 0.f;
#pragma unroll
  for (int t = 0; t < 6; ++t) { x[t] = sr[lane + 64*t]; sum += x[t]; sq += x[t]*x[t]; }
#pragma unroll
  for (int off = 32; off; off >>= 1) { sum += __shfl_down(sum, off); sq += __shfl_down(sq, off); }
  sum = __shfl(sum, 0); sq = __shfl(sq, 0);
  float mean = sum * (1.f/CS);
  float var  = sq  * (1.f/CS) - mean*mean;
  float rstd = rsqrtf(var + 1e-5f);
  unsigned short* orow = s_ln_bf + (size_t)row * CS;
#pragma unroll
  for (int t = 0; t < 6; ++t) orow[lane + 64*t] = f2bf((x[t]-mean)*rstd);
}

// ---------------------------------------------------------------------------
// LN(a) + adaLN modulation for both attention (amod) and transition (tmod).
// bf16 outputs (GEMM inputs).
// ---------------------------------------------------------------------------
__global__ __launch_bounds__(256) void modln_kernel(const float* __restrict__ a,
                                                    const float* __restrict__ sp0,
                                                    const float* __restrict__ sp1,
                                                    const float* __restrict__ sp3,
                                                    const float* __restrict__ sp4,
                                                    unsigned short* __restrict__ amod,
                                                    unsigned short* __restrict__ tmod) {
  int row  = blockIdx.x * 4 + (threadIdx.x >> 6);
  int lane = threadIdx.x & 63;
  const float* ar = a + (size_t)row * CA;
  float x0 = ar[lane], x1 = ar[lane + 64];
  float sum = x0 + x1, sq = x0*x0 + x1*x1;
#pragma unroll
  for (int off = 32; off; off >>= 1) { sum += __shfl_down(sum, off); sq += __shfl_down(sq, off); }
  sum = __shfl(sum, 0); sq = __shfl(sq, 0);
  float mean = sum * (1.f/CA);
  float var  = sq  * (1.f/CA) - mean*mean;
  float rstd = rsqrtf(var + 1e-5f);
  float n0 = (x0-mean)*rstd, n1 = (x1-mean)*rstd;
  size_t i0 = (size_t)row * CA + lane;
  amod[i0]      = f2bf(sp0[i0]     *n0 + sp1[i0]);
  amod[i0 + 64] = f2bf(sp0[i0 + 64]*n1 + sp1[i0 + 64]);
  tmod[i0]      = f2bf(sp3[i0]     *n0 + sp4[i0]);
  tmod[i0 + 64] = f2bf(sp3[i0 + 64]*n1 + sp4[i0 + 64]);
}

// ---------------------------------------------------------------------------
// Weight transpose+convert: src fp32 K x N (row-major)  ->  dst bf16 N x K.
// ---------------------------------------------------------------------------
struct TJob { const float* src; unsigned short* dst; int K; int N; };
struct TJobs { TJob j[42]; };

__global__ __launch_bounds__(256) void transpose_bf16(TJobs jobs) {
  TJob jb = jobs.j[blockIdx.z];
  int tk = blockIdx.x * 32, tn = blockIdx.y * 32;
  if (tk >= jb.K || tn >= jb.N) return;
  __shared__ float tile[32][33];
  int tx = threadIdx.x & 31;
  int ty = threadIdx.x >> 5;   // 0..7
#pragma unroll
  for (int r = ty; r < 32; r += 8) tile[r][tx] = jb.src[(size_t)(tk + r) * jb.N + tn + tx];
  __syncthreads();
#pragma unroll
  for (int r = ty; r < 32; r += 8)
    jb.dst[(size_t)(tn + r) * jb.K + tk + tx] = f2bf(tile[tx][r]);
}

// ---------------------------------------------------------------------------
// bf16 MFMA GEMM: C(MxN) = A(MxK) @ B(KxN), A bf16 row-major, B given
// TRANSPOSED bf16 (N x K).  128x128 block tile, BK=32, 4 waves (2x2 of 64x64).
// LDS layout: chunked [k-chunk][row][8 bf16], chunk stride 1032 ushorts.
// modes: 0 = +bias(optional), 1 = sigmoid(+bias), 2 = *gate, 3 = *gate + out,
//        4 (DUAL) = silu(A@B) * (A@B2) -> bf16 out
// ---------------------------------------------------------------------------
struct GemmJob {
  const unsigned short* Bt;
  const unsigned short* Bt2;
  const float* bias;
  const float* gate;
  float* outf;
  unsigned short* outbf;
  int mode;
  int pad;
};
struct GemmJobs { GemmJob j[6]; };

#define CH_STRIDE 1032   // ushorts per k-chunk plane (128*8 + 8 pad)

template <bool DUAL>
__global__ __launch_bounds__(256) void gemm_mfma(const unsigned short* __restrict__ A,
                                                 int K, int Nn, GemmJobs jobs) {
  GemmJob jb = jobs.j[blockIdx.z];
  const int bm = blockIdx.y * 128, bn = blockIdx.x * 128;

  __shared__ unsigned short As[4 * CH_STRIDE];
  __shared__ unsigned short Bs[4 * CH_STRIDE];
  __shared__ unsigned short Bs2[DUAL ? 4 * CH_STRIDE : 8];

  const int tid  = threadIdx.x;
  const int lane = tid & 63;
  const int wave = tid >> 6;
  const int wr = wave >> 1, wc = wave & 1;
  const int l15 = lane & 15, quad = lane >> 4;

  floatx4 acc[4][4] = {};
  floatx4 acc2[DUAL ? 4 : 1][DUAL ? 4 : 1] = {};

  for (int k0 = 0; k0 < K; k0 += 32) {
    __syncthreads();
#pragma unroll
    for (int h = 0; h < 2; ++h) {
      int f = tid + 256 * h;
      int m = f >> 2, c = f & 3;
      uint4 av = *(const uint4*)(A + (size_t)(bm + m) * K + k0 + c * 8);
      *(uint4*)(As + c * CH_STRIDE + m * 8) = av;
      uint4 bv = *(const uint4*)(jb.Bt + (size_t)(bn + m) * K + k0 + c * 8);
      *(uint4*)(Bs + c * CH_STRIDE + m * 8) = bv;
      if constexpr (DUAL) {
        uint4 bv2 = *(const uint4*)(jb.Bt2 + (size_t)(bn + m) * K + k0 + c * 8);
        *(uint4*)(Bs2 + c * CH_STRIDE + m * 8) = bv2;
      }
    }
    __syncthreads();

    short8 a_frag[4], b_frag[4];
#pragma unroll
    for (int mt = 0; mt < 4; ++mt)
      a_frag[mt] = *(const short8*)(As + quad * CH_STRIDE + (wr * 64 + mt * 16 + l15) * 8);
#pragma unroll
    for (int nt = 0; nt < 4; ++nt)
      b_frag[nt] = *(const short8*)(Bs + quad * CH_STRIDE + (wc * 64 + nt * 16 + l15) * 8);
#pragma unroll
    for (int mt = 0; mt < 4; ++mt)
#pragma unroll
      for (int nt = 0; nt < 4; ++nt)
        acc[mt][nt] = __builtin_amdgcn_mfma_f32_16x16x32_bf16(a_frag[mt], b_frag[nt], acc[mt][nt], 0, 0, 0);
    if constexpr (DUAL) {
      short8 b2_frag[4];
#pragma unroll
      for (int nt = 0; nt < 4; ++nt)
        b2_frag[nt] = *(const short8*)(Bs2 + quad * CH_STRIDE + (wc * 64 + nt * 16 + l15) * 8);
#pragma unroll
      for (int mt = 0; mt < 4; ++mt)
#pragma unroll
        for (int nt = 0; nt < 4; ++nt)
          acc2[mt][nt] = __builtin_amdgcn_mfma_f32_16x16x32_bf16(a_frag[mt], b2_frag[nt], acc2[mt][nt], 0, 0, 0);
    }
  }

  // Epilogue.  C/D layout: col = lane&15, row = quad*4 + reg.
#pragma unroll
  for (int mt = 0; mt < 4; ++mt) {
#pragma unroll
    for (int nt = 0; nt < 4; ++nt) {
      int n = bn + wc * 64 + nt * 16 + l15;
      int mbase = bm + wr * 64 + mt * 16 + quad * 4;
      floatx4 v = acc[mt][nt];
      if constexpr (DUAL) {
        floatx4 v2 = acc2[mt][nt];
#pragma unroll
        for (int r = 0; r < 4; ++r) {
          size_t idx = (size_t)(mbase + r) * Nn + n;
          float x1 = v[r];
          jb.outbf[idx] = f2bf(x1 * sigmoidf_(x1) * v2[r]);
        }
      } else {
        float bias = (jb.mode <= 1 && jb.bias) ? jb.bias[n] : 0.f;
#pragma unroll
        for (int r = 0; r < 4; ++r) {
          size_t idx = (size_t)(mbase + r) * Nn + n;
          float x = v[r];
          switch (jb.mode) {
            case 0: x += bias; break;
            case 1: x = sigmoidf_(x + bias); break;
            case 2: x = x * jb.gate[idx]; break;
            case 3: x = x * jb.gate[idx] + jb.outf[idx]; break;
          }
          jb.outf[idx] = x;
        }
      }
    }
  }
}

// ---------------------------------------------------------------------------
// Pair bias: bias[b,w,q,k,h] = LN16(p[b,w,q,k,:]) @ (lnz_w*wb) + lnz_b@wb
// ---------------------------------------------------------------------------
__global__ __launch_bounds__(256) void bias_kernel(const float* __restrict__ p,
                                                   const float* __restrict__ lnz_w,
                                                   const float* __restrict__ lnz_b,
                                                   const float* __restrict__ wb,
                                                   float* __restrict__ biasb) {
  __shared__ float effW[16][4];
  __shared__ float effb[4];
  int tid = threadIdx.x;
  if (tid < 64) effW[tid >> 2][tid & 3] = lnz_w[tid >> 2] * wb[tid];
  if (tid < 4) {
    float acc = 0.f;
    for (int z = 0; z < 16; ++z) acc += lnz_b[z] * wb[z*4 + tid];
    effb[tid] = acc;
  }
  __syncthreads();
  size_t t = (size_t)blockIdx.x * 256 + tid;
  const float4* pr = (const float4*)(p + t * 16);
  float4 p0 = pr[0], p1 = pr[1], p2 = pr[2], p3 = pr[3];
  float x[16] = {p0.x,p0.y,p0.z,p0.w, p1.x,p1.y,p1.z,p1.w,
                 p2.x,p2.y,p2.z,p2.w, p3.x,p3.y,p3.z,p3.w};
  float sum = 0.f, sq = 0.f;
#pragma unroll
  for (int z = 0; z < 16; ++z) { sum += x[z]; sq += x[z]*x[z]; }
  float mean = sum * (1.f/16.f);
  float var  = sq  * (1.f/16.f) - mean*mean;
  float rstd = rsqrtf(var + 1e-5f);
  float o[4];
#pragma unroll
  for (int hh = 0; hh < 4; ++hh) {
    float acc = effb[hh];
#pragma unroll
    for (int z = 0; z < 16; ++z) acc += (x[z]-mean)*rstd * effW[z][hh];
    o[hh] = acc;
  }
  *(float4*)(biasb + t*4) = make_float4(o[0], o[1], o[2], o[3]);
}

// ---------------------------------------------------------------------------
// Windowed attention: one block per (b, w, h).  fp32 math, bf16 gated output.
// ---------------------------------------------------------------------------
__global__ __launch_bounds__(256) void attn_kernel(const float* __restrict__ Qb,
                                                   const float* __restrict__ Kb,
                                                   const float* __restrict__ Vb,
                                                   const float* __restrict__ Gb,
                                                   const float* __restrict__ biasb,
                                                   unsigned short* __restrict__ Ob) {
  const int w = blockIdx.x, h = blockIdx.y, b = blockIdx.z;
  __shared__ float Qs[32][33];
  __shared__ float Ks[128][33];
  __shared__ float Vs[128][33];
  __shared__ float Ls[32][132];
  __shared__ float redm[32][8];
  __shared__ float reds[32][8];
  const int tid = threadIdx.x;

  {
    int qq = tid >> 3, dg = (tid & 7) * 4;
    float4 v = *(const float4*)(Qb + (size_t)(b*NN + w*NQW + qq) * CA + h*DD + dg);
    Qs[qq][dg] = v.x; Qs[qq][dg+1] = v.y; Qs[qq][dg+2] = v.z; Qs[qq][dg+3] = v.w;
  }
#pragma unroll
  for (int ii = 0; ii < 4; ++ii) {
    int f = tid + 256*ii;
    int j = f >> 3, dg = (f & 7) * 4;
    int r = w*NQW - 48 + j;
    float4 kv = {0,0,0,0}, vv = {0,0,0,0};
    if (r >= 0 && r < NN) {
      size_t base = (size_t)(b*NN + r) * CA + h*DD + dg;
      kv = *(const float4*)(Kb + base);
      vv = *(const float4*)(Vb + base);
    }
    Ks[j][dg]=kv.x; Ks[j][dg+1]=kv.y; Ks[j][dg+2]=kv.z; Ks[j][dg+3]=kv.w;
    Vs[j][dg]=vv.x; Vs[j][dg+1]=vv.y; Vs[j][dg+2]=vv.z; Vs[j][dg+3]=vv.w;
  }
  __syncthreads();

  const int qq = tid >> 3, sub = tid & 7;
  const float invd = 0.17677669529663687f; // 1/sqrt(32)
  const float* brow = biasb + (size_t)((b*WW + w)*NQW + qq) * (NKW*HH) + h;
  float lmax = -3.4e38f;
#pragma unroll
  for (int jj = 0; jj < 16; ++jj) {
    int j = sub + jj*8;
    float acc = 0.f;
#pragma unroll
    for (int d = 0; d < 32; ++d) acc = fmaf(Qs[qq][d], Ks[j][d], acc);
    int r = w*NQW - 48 + j;
    float l = (r >= 0 && r < NN) ? acc * invd + brow[(size_t)j*HH] : -1e9f;
    Ls[qq][j] = l;
    lmax = fmaxf(lmax, l);
  }
  redm[qq][sub] = lmax;
  __syncthreads();
  float m = redm[qq][0];
#pragma unroll
  for (int t2 = 1; t2 < 8; ++t2) m = fmaxf(m, redm[qq][t2]);
  float lsum = 0.f;
#pragma unroll
  for (int jj = 0; jj < 16; ++jj) {
    int j = sub + jj*8;
    float e = expf(Ls[qq][j] - m);
    Ls[qq][j] = e;
    lsum += e;
  }
  reds[qq][sub] = lsum;
  __syncthreads();
  float ssum = 0.f;
#pragma unroll
  for (int t2 = 0; t2 < 8; ++t2) ssum += reds[qq][t2];
  float invs = 1.f / ssum;

  const int dg = sub * 4;
  float acc[4] = {0.f, 0.f, 0.f, 0.f};
  for (int j = 0; j < 128; ++j) {
    float pv = Ls[qq][j];
#pragma unroll
    for (int dd = 0; dd < 4; ++dd) acc[dd] = fmaf(pv, Vs[j][dg+dd], acc[dd]);
  }
  size_t obase = (size_t)(b*NN + w*NQW + qq) * CA + h*DD + dg;
  float4 gv = *(const float4*)(Gb + obase);
  ushort4 ov;
  ov.x = f2bf(gv.x * acc[0] * invs);
  ov.y = f2bf(gv.y * acc[1] * invs);
  ov.z = f2bf(gv.z * acc[2] * invs);
  ov.w = f2bf(gv.w * acc[3] * invs);
  *(ushort4*)(Ob + obase) = ov;
}

// ---------------------------------------------------------------------------
// Host-side orchestration.
// ---------------------------------------------------------------------------
extern "C" void kernel_launch(void* const* d_in, const int* in_sizes, int n_in,
                              void* d_out, int out_size, void* d_ws, size_t ws_size,
                              hipStream_t stream) {
  const float* q             = (const float*)d_in[0];
  const float* s             = (const float*)d_in[1];
  const float* p             = (const float*)d_in[2];
  const float* adaln_scale_w = (const float*)d_in[3];
  const float* adaln_scale_b = (const float*)d_in[4];
  const float* adaln_shift_w = (const float*)d_in[5];
  const float* wq            = (const float*)d_in[6];
  const float* bq            = (const float*)d_in[7];
  const float* wk            = (const float*)d_in[8];
  const float* wv            = (const float*)d_in[9];
  const float* lnz_w         = (const float*)d_in[10];
  const float* lnz_b         = (const float*)d_in[11];
  const float* wb_pair       = (const float*)d_in[12];
  const float* wg            = (const float*)d_in[13];
  const float* wo            = (const float*)d_in[14];
  const float* sgate_w       = (const float*)d_in[15];
  const float* sgate_b       = (const float*)d_in[16];
  const float* t_scale_w     = (const float*)d_in[17];
  const float* t_scale_b     = (const float*)d_in[18];
  const float* t_shift_w     = (const float*)d_in[19];
  const float* t_wa          = (const float*)d_in[20];
  const float* t_wb          = (const float*)d_in[21];
  const float* t_wo          = (const float*)d_in[22];
  const float* t_sgate_w     = (const float*)d_in[23];
  const float* t_sgate_b     = (const float*)d_in[24];
  float* out = (float*)d_out;

  const size_t MC = (size_t)MR * CA; // 2097152
  float* fws = (float*)d_ws;
  float* biasb = fws;                               // 16.78M floats
  float* SP    = biasb + (size_t)BB*WW*NQW*NKW*HH;  // 6*MC
  float* Qb    = SP + 6*MC;
  float* Kb    = Qb + MC;
  float* Vb    = Kb + MC;
  float* Gb    = Vb + MC;
  float* abuf0 = Gb + MC;
  float* abuf1 = abuf0 + MC;
  unsigned short* uws = (unsigned short*)(abuf1 + MC);
  unsigned short* s_ln_bf = uws;                    // MR*CS
  unsigned short* amod_bf = s_ln_bf + (size_t)MR*CS;
  unsigned short* tmod_bf = amod_bf + MC;
  unsigned short* Ob_bf   = tmod_bf + MC;
  unsigned short* HID_bf  = Ob_bf + MC;             // MR*HIDN
  unsigned short* wbuf    = HID_bf + (size_t)MR*HIDN;

  // Per-block transposed-weight offsets within wbuf
  const size_t WBLK = 6*(size_t)CA*CS + 5*(size_t)CA*CA + 3*(size_t)CA*HIDN;
  const size_t o_ascale = 0;
  const size_t o_ashift = o_ascale + (size_t)CA*CS;
  const size_t o_sgate  = o_ashift + (size_t)CA*CS;
  const size_t o_tscale = o_sgate  + (size_t)CA*CS;
  const size_t o_tshift = o_tscale + (size_t)CA*CS;
  const size_t o_tsgate = o_tshift + (size_t)CA*CS;
  const size_t o_wq     = o_tsgate + (size_t)CA*CS;
  const size_t o_wk     = o_wq + (size_t)CA*CA;
  const size_t o_wv     = o_wk + (size_t)CA*CA;
  const size_t o_wg     = o_wv + (size_t)CA*CA;
  const size_t o_wo     = o_wg + (size_t)CA*CA;
  const size_t o_twa    = o_wo + (size_t)CA*CA;
  const size_t o_twb    = o_twa + (size_t)HIDN*CA;
  const size_t o_two    = o_twb + (size_t)HIDN*CA;

  // ---- one-time: LN(s), weight transpose/convert ----
  ln_s_kernel<<<MR/4, 256, 0, stream>>>(s, s_ln_bf);

  TJobs tj;
  for (int i = 0; i < NBLK; ++i) {
    unsigned short* wb0 = wbuf + (size_t)i * WBLK;
    int b14 = i * 14;
    tj.j[b14+0]  = TJob{adaln_scale_w + (size_t)i*CS*CA, wb0 + o_ascale, CS, CA};
    tj.j[b14+1]  = TJob{adaln_shift_w + (size_t)i*CS*CA, wb0 + o_ashift, CS, CA};
    tj.j[b14+2]  = TJob{sgate_w       + (size_t)i*CS*CA, wb0 + o_sgate,  CS, CA};
    tj.j[b14+3]  = TJob{t_scale_w     + (size_t)i*CS*CA, wb0 + o_tscale, CS, CA};
    tj.j[b14+4]  = TJob{t_shift_w     + (size_t)i*CS*CA, wb0 + o_tshift, CS, CA};
    tj.j[b14+5]  = TJob{t_sgate_w     + (size_t)i*CS*CA, wb0 + o_tsgate, CS, CA};
    tj.j[b14+6]  = TJob{wq   + (size_t)i*CA*CA,   wb0 + o_wq,  CA, CA};
    tj.j[b14+7]  = TJob{wk   + (size_t)i*CA*CA,   wb0 + o_wk,  CA, CA};
    tj.j[b14+8]  = TJob{wv   + (size_t)i*CA*CA,   wb0 + o_wv,  CA, CA};
    tj.j[b14+9]  = TJob{wg   + (size_t)i*CA*CA,   wb0 + o_wg,  CA, CA};
    tj.j[b14+10] = TJob{wo   + (size_t)i*CA*CA,   wb0 + o_wo,  CA, CA};
    tj.j[b14+11] = TJob{t_wa + (size_t)i*CA*HIDN, wb0 + o_twa, CA, HIDN};
    tj.j[b14+12] = TJob{t_wb + (size_t)i*CA*HIDN, wb0 + o_twb, CA, HIDN};
    tj.j[b14+13] = TJob{t_wo + (size_t)i*HIDN*CA, wb0 + o_two, HIDN, CA};
  }
  transpose_bf16<<<dim3(12, 8, 42), 256, 0, stream>>>(tj);

  for (int i = 0; i < NBLK; ++i) {
    const float* a_in = (i == 0) ? q : (i == 1 ? abuf0 : abuf1);
    float* a_out = (i == 2) ? out : (i == 0 ? abuf0 : abuf1);
    unsigned short* wb0 = wbuf + (size_t)i * WBLK;

    // 6 projections of s_ln (K=384 -> N=128 each)
    GemmJobs js = {};
    js.j[0] = GemmJob{wb0 + o_ascale, nullptr, adaln_scale_b + i*CA, nullptr, SP + 0*MC, nullptr, 1, 0};
    js.j[1] = GemmJob{wb0 + o_ashift, nullptr, nullptr,              nullptr, SP + 1*MC, nullptr, 0, 0};
    js.j[2] = GemmJob{wb0 + o_sgate,  nullptr, sgate_b   + i*CA,     nullptr, SP + 2*MC, nullptr, 1, 0};
    js.j[3] = GemmJob{wb0 + o_tscale, nullptr, t_scale_b + i*CA,     nullptr, SP + 3*MC, nullptr, 1, 0};
    js.j[4] = GemmJob{wb0 + o_tshift, nullptr, nullptr,              nullptr, SP + 4*MC, nullptr, 0, 0};
    js.j[5] = GemmJob{wb0 + o_tsgate, nullptr, t_sgate_b + i*CA,     nullptr, SP + 5*MC, nullptr, 1, 0};
    gemm_mfma<false><<<dim3(1, MR/128, 6), 256, 0, stream>>>(s_ln_bf, CS, CA, js);

    // LN(a) + both modulations -> bf16
    modln_kernel<<<MR/4, 256, 0, stream>>>(a_in, SP + 0*MC, SP + 1*MC, SP + 3*MC, SP + 4*MC,
                                           amod_bf, tmod_bf);

    // Q, K, V, G projections (K=128 -> N=128, fp32 outs for attention)
    GemmJobs jq = {};
    jq.j[0] = GemmJob{wb0 + o_wq, nullptr, bq + i*CA, nullptr, Qb, nullptr, 0, 0};
    jq.j[1] = GemmJob{wb0 + o_wk, nullptr, nullptr,   nullptr, Kb, nullptr, 0, 0};
    jq.j[2] = GemmJob{wb0 + o_wv, nullptr, nullptr,   nullptr, Vb, nullptr, 0, 0};
    jq.j[3] = GemmJob{wb0 + o_wg, nullptr, nullptr,   nullptr, Gb, nullptr, 1, 0};
    gemm_mfma<false><<<dim3(1, MR/128, 4), 256, 0, stream>>>(amod_bf, CA, CA, jq);

    // pair bias from p
    bias_kernel<<<(BB*WW*NQW*NKW)/256, 256, 0, stream>>>(
        p, lnz_w + i*CZ, lnz_b + i*CZ, wb_pair + (size_t)i*CZ*HH, biasb);

    // windowed attention (g-gated, bf16 out)
    attn_kernel<<<dim3(WW, HH, BB), 256, 0, stream>>>(Qb, Kb, Vb, Gb, biasb, Ob_bf);

    // attn_out = (O @ wo) * sgate  -> a_out
    GemmJobs ja = {};
    ja.j[0] = GemmJob{wb0 + o_wo, nullptr, nullptr, SP + 2*MC, a_out, nullptr, 2, 0};
    gemm_mfma<false><<<dim3(1, MR/128, 1), 256, 0, stream>>>(Ob_bf, CA, CA, ja);

    // hidden = silu(tmod @ t_wa) * (tmod @ t_wb)  -> bf16 (K=128 -> N=256)
    GemmJobs jh = {};
    jh.j[0] = GemmJob{wb0 + o_twa, wb0 + o_twb, nullptr, nullptr, nullptr, HID_bf, 4, 0};
    gemm_mfma<true><<<dim3(2, MR/128, 1), 256, 0, stream>>>(tmod_bf, CA, HIDN, jh);

    // a_out += (hidden @ t_wo) * t_sgate   (K=256 -> N=128)
    GemmJobs jt = {};
    jt.j[0] = GemmJob{wb0 + o_two, nullptr, nullptr, SP + 5*MC, a_out, nullptr, 3, 0};
    gemm_mfma<false><<<dim3(1, MR/128, 1), 256, 0, stream>>>(HID_bf, HIDN, CA, jt);
  }
}

// Round 3
// 703.322 us; speedup vs baseline: 2.7072x; 1.2230x over previous
//
#include <hip/hip_runtime.h>
#include <hip/hip_bf16.h>
#include <cstddef>
#include <cstdint>

// Problem constants
#define BB   2
#define NN   8192
#define CA   128
#define CS   384
#define CZ   16
#define HH   4
#define DD   32
#define NQW  32      // NQ
#define NKW  128     // NK
#define NBLK 3
#define WW   256     // N / NQ
#define MR   (BB*NN) // 16384 rows
#define HIDN 256     // 2*CA

typedef unsigned short u16;
typedef __attribute__((ext_vector_type(8))) short short8;
typedef __attribute__((ext_vector_type(4))) float floatx4;

__device__ __forceinline__ float sigmoidf_(float x) { return 1.f / (1.f + __expf(-x)); }

__device__ __forceinline__ u16 f2bf(float x) {
  unsigned u = __float_as_uint(x);
  unsigned r = (u + 0x7fffu + ((u >> 16) & 1u)) >> 16;
  return (u16)r;
}
__device__ __forceinline__ float bf2f(u16 u) {
  return __uint_as_float(((unsigned)u) << 16);
}

// ---------------------------------------------------------------------------
// LayerNorm of s (C_S = 384), one wave per row -> bf16 out.
// ---------------------------------------------------------------------------
__global__ __launch_bounds__(256) void ln_s_kernel(const float* __restrict__ s,
                                                   u16* __restrict__ s_ln_bf) {
  int row  = blockIdx.x * 4 + (threadIdx.x >> 6);
  int lane = threadIdx.x & 63;
  const float* sr = s + (size_t)row * CS;
  float x[6];
  float sum = 0.f, sq = 0.f;
#pragma unroll
  for (int t = 0; t < 6; ++t) { x[t] = sr[lane + 64*t]; sum += x[t]; sq += x[t]*x[t]; }
#pragma unroll
  for (int off = 32; off; off >>= 1) { sum += __shfl_down(sum, off); sq += __shfl_down(sq, off); }
  sum = __shfl(sum, 0); sq = __shfl(sq, 0);
  float mean = sum * (1.f/CS);
  float var  = sq  * (1.f/CS) - mean*mean;
  float rstd = rsqrtf(var + 1e-5f);
  u16* orow = s_ln_bf + (size_t)row * CS;
#pragma unroll
  for (int t = 0; t < 6; ++t) orow[lane + 64*t] = f2bf((x[t]-mean)*rstd);
}

// ---------------------------------------------------------------------------
// LN(a) + adaLN modulation for attention (amod) and transition (tmod), bf16.
// ---------------------------------------------------------------------------
__global__ __launch_bounds__(256) void modln_kernel(const float* __restrict__ a,
                                                    const u16* __restrict__ sp0,
                                                    const u16* __restrict__ sp1,
                                                    const u16* __restrict__ sp3,
                                                    const u16* __restrict__ sp4,
                                                    u16* __restrict__ amod,
                                                    u16* __restrict__ tmod) {
  int row  = blockIdx.x * 4 + (threadIdx.x >> 6);
  int lane = threadIdx.x & 63;
  const float* ar = a + (size_t)row * CA;
  float x0 = ar[lane], x1 = ar[lane + 64];
  float sum = x0 + x1, sq = x0*x0 + x1*x1;
#pragma unroll
  for (int off = 32; off; off >>= 1) { sum += __shfl_down(sum, off); sq += __shfl_down(sq, off); }
  sum = __shfl(sum, 0); sq = __shfl(sq, 0);
  float mean = sum * (1.f/CA);
  float var  = sq  * (1.f/CA) - mean*mean;
  float rstd = rsqrtf(var + 1e-5f);
  float n0 = (x0-mean)*rstd, n1 = (x1-mean)*rstd;
  size_t i0 = (size_t)row * CA + lane;
  amod[i0]      = f2bf(bf2f(sp0[i0])     *n0 + bf2f(sp1[i0]));
  amod[i0 + 64] = f2bf(bf2f(sp0[i0 + 64])*n1 + bf2f(sp1[i0 + 64]));
  tmod[i0]      = f2bf(bf2f(sp3[i0])     *n0 + bf2f(sp4[i0]));
  tmod[i0 + 64] = f2bf(bf2f(sp3[i0 + 64])*n1 + bf2f(sp4[i0 + 64]));
}

// ---------------------------------------------------------------------------
// Weight transpose+convert: src fp32 K x N (row-major)  ->  dst bf16 N x K.
// ---------------------------------------------------------------------------
struct TJob { const float* src; u16* dst; int K; int N; };
struct TJobs { TJob j[42]; };

__global__ __launch_bounds__(256) void transpose_bf16(TJobs jobs) {
  TJob jb = jobs.j[blockIdx.z];
  int tk = blockIdx.x * 32, tn = blockIdx.y * 32;
  if (tk >= jb.K || tn >= jb.N) return;
  __shared__ float tile[32][33];
  int tx = threadIdx.x & 31;
  int ty = threadIdx.x >> 5;
#pragma unroll
  for (int r = ty; r < 32; r += 8) tile[r][tx] = jb.src[(size_t)(tk + r) * jb.N + tn + tx];
  __syncthreads();
#pragma unroll
  for (int r = ty; r < 32; r += 8)
    jb.dst[(size_t)(tn + r) * jb.K + tk + tx] = f2bf(tile[tx][r]);
}

// ---------------------------------------------------------------------------
// bf16 MFMA GEMM.  128x128 block tile, BK=32, 4 waves (2x2 of 64x64).
// modes: 0 = (+bias)->bf16, 1 = sigmoid(+bias)->bf16, 2 = *gate(bf16)->f32,
//        3 = *gate + out -> f32, 4 (DUAL) = silu(A@B)*(A@B2) -> bf16,
//        5 = transposed bf16 write (V): out[b][n][token]
// ---------------------------------------------------------------------------
struct GemmJob {
  const u16* Bt;
  const u16* Bt2;
  const float* bias;
  const u16* gate;
  float* outf;
  u16* outbf;
  int mode;
  int pad;
};
struct GemmJobs { GemmJob j[6]; };

#define CH_STRIDE 1032   // ushorts per k-chunk plane (128*8 + 8 pad)

template <bool DUAL>
__global__ __launch_bounds__(256) void gemm_mfma(const u16* __restrict__ A,
                                                 int K, int Nn, GemmJobs jobs) {
  GemmJob jb = jobs.j[blockIdx.z];
  const int bm = blockIdx.y * 128, bn = blockIdx.x * 128;

  __shared__ u16 As[4 * CH_STRIDE];
  __shared__ u16 Bs[4 * CH_STRIDE];
  __shared__ u16 Bs2[DUAL ? 4 * CH_STRIDE : 8];

  const int tid  = threadIdx.x;
  const int lane = tid & 63;
  const int wave = tid >> 6;
  const int wr = wave >> 1, wc = wave & 1;
  const int l15 = lane & 15, quad = lane >> 4;

  floatx4 acc[4][4] = {};
  floatx4 acc2[DUAL ? 4 : 1][DUAL ? 4 : 1] = {};

  for (int k0 = 0; k0 < K; k0 += 32) {
    __syncthreads();
#pragma unroll
    for (int h = 0; h < 2; ++h) {
      int f = tid + 256 * h;
      int m = f >> 2, c = f & 3;
      uint4 av = *(const uint4*)(A + (size_t)(bm + m) * K + k0 + c * 8);
      *(uint4*)(As + c * CH_STRIDE + m * 8) = av;
      uint4 bv = *(const uint4*)(jb.Bt + (size_t)(bn + m) * K + k0 + c * 8);
      *(uint4*)(Bs + c * CH_STRIDE + m * 8) = bv;
      if constexpr (DUAL) {
        uint4 bv2 = *(const uint4*)(jb.Bt2 + (size_t)(bn + m) * K + k0 + c * 8);
        *(uint4*)(Bs2 + c * CH_STRIDE + m * 8) = bv2;
      }
    }
    __syncthreads();

    short8 a_frag[4], b_frag[4];
#pragma unroll
    for (int mt = 0; mt < 4; ++mt)
      a_frag[mt] = *(const short8*)(As + quad * CH_STRIDE + (wr * 64 + mt * 16 + l15) * 8);
#pragma unroll
    for (int nt = 0; nt < 4; ++nt)
      b_frag[nt] = *(const short8*)(Bs + quad * CH_STRIDE + (wc * 64 + nt * 16 + l15) * 8);
#pragma unroll
    for (int mt = 0; mt < 4; ++mt)
#pragma unroll
      for (int nt = 0; nt < 4; ++nt)
        acc[mt][nt] = __builtin_amdgcn_mfma_f32_16x16x32_bf16(a_frag[mt], b_frag[nt], acc[mt][nt], 0, 0, 0);
    if constexpr (DUAL) {
      short8 b2_frag[4];
#pragma unroll
      for (int nt = 0; nt < 4; ++nt)
        b2_frag[nt] = *(const short8*)(Bs2 + quad * CH_STRIDE + (wc * 64 + nt * 16 + l15) * 8);
#pragma unroll
      for (int mt = 0; mt < 4; ++mt)
#pragma unroll
        for (int nt = 0; nt < 4; ++nt)
          acc2[mt][nt] = __builtin_amdgcn_mfma_f32_16x16x32_bf16(a_frag[mt], b2_frag[nt], acc2[mt][nt], 0, 0, 0);
    }
  }

  // Epilogue.  C/D layout: col = lane&15, row = quad*4 + reg.
#pragma unroll
  for (int mt = 0; mt < 4; ++mt) {
#pragma unroll
    for (int nt = 0; nt < 4; ++nt) {
      int n = bn + wc * 64 + nt * 16 + l15;
      int mbase = bm + wr * 64 + mt * 16 + quad * 4;
      floatx4 v = acc[mt][nt];
      if constexpr (DUAL) {
        floatx4 v2 = acc2[mt][nt];
#pragma unroll
        for (int r = 0; r < 4; ++r) {
          size_t idx = (size_t)(mbase + r) * Nn + n;
          float x1 = v[r];
          jb.outbf[idx] = f2bf(x1 * sigmoidf_(x1) * v2[r]);
        }
      } else if (jb.mode == 5) {
        int bidx = mbase >> 13;          // m / NN
        int tok  = mbase & (NN - 1);
        ushort4 o;
        o.x = f2bf(v[0]); o.y = f2bf(v[1]); o.z = f2bf(v[2]); o.w = f2bf(v[3]);
        *(ushort4*)(jb.outbf + (size_t)(bidx * CA + n) * NN + tok) = o;
      } else {
        float bias = (jb.mode <= 1 && jb.bias) ? jb.bias[n] : 0.f;
#pragma unroll
        for (int r = 0; r < 4; ++r) {
          size_t idx = (size_t)(mbase + r) * Nn + n;
          float x = v[r];
          switch (jb.mode) {
            case 0: jb.outbf[idx] = f2bf(x + bias); break;
            case 1: jb.outbf[idx] = f2bf(sigmoidf_(x + bias)); break;
            case 2: jb.outf[idx] = x * bf2f(jb.gate[idx]); break;
            case 3: jb.outf[idx] = x * bf2f(jb.gate[idx]) + jb.outf[idx]; break;
          }
        }
      }
    }
  }
}

// ---------------------------------------------------------------------------
// Pair bias for ALL 3 blocks in one pass over p.
// Output layout: biasT[i][b][w][h][k][q] (bf16), block = (b,w).
// ---------------------------------------------------------------------------
__global__ __launch_bounds__(256) void bias3_kernel(const float* __restrict__ p,
                                                    const float* __restrict__ lnz_w,
                                                    const float* __restrict__ lnz_b,
                                                    const float* __restrict__ wb,
                                                    u16* __restrict__ biasT) {
  const int w = blockIdx.x, b = blockIdx.y;
  __shared__ float effW[12][16];
  __shared__ float effb[12];
  __shared__ u16 tile[12 * 32 * 40];
  const int t = threadIdx.x;
  if (t < 192) {
    int i = t >> 6, rem = t & 63, z = rem >> 2, hh = rem & 3;
    effW[i*4 + hh][z] = lnz_w[i*CZ + z] * wb[(i*CZ + z)*HH + hh];
  }
  if (t < 12) {
    int i = t >> 2, hh = t & 3;
    float acc = 0.f;
    for (int z = 0; z < 16; ++z) acc += lnz_b[i*CZ + z] * wb[(i*CZ + z)*HH + hh];
    effb[t] = acc;
  }
  __syncthreads();

  const int kk = t & 31, qg = (t >> 5) * 4;
  for (int kc = 0; kc < 4; ++kc) {
    int k = kc * 32 + kk;
    u16 out4[12][4];
#pragma unroll
    for (int r = 0; r < 4; ++r) {
      int qq = qg + r;
      const float4* pr = (const float4*)(p + (size_t)(((b * WW + w) * NQW + qq) * NKW + k) * 16);
      float4 p0 = pr[0], p1 = pr[1], p2 = pr[2], p3 = pr[3];
      float x[16] = {p0.x,p0.y,p0.z,p0.w, p1.x,p1.y,p1.z,p1.w,
                     p2.x,p2.y,p2.z,p2.w, p3.x,p3.y,p3.z,p3.w};
      float sum = 0.f, sq = 0.f;
#pragma unroll
      for (int z = 0; z < 16; ++z) { sum += x[z]; sq += x[z]*x[z]; }
      float mean = sum * (1.f/16.f);
      float var  = sq  * (1.f/16.f) - mean*mean;
      float rstd = rsqrtf(var + 1e-5f);
#pragma unroll
      for (int ih = 0; ih < 12; ++ih) {
        float acc = effb[ih];
#pragma unroll
        for (int z = 0; z < 16; ++z) acc += (x[z]-mean)*rstd * effW[ih][z];
        out4[ih][r] = f2bf(acc);
      }
    }
    __syncthreads();   // previous chunk's readers done
#pragma unroll
    for (int ih = 0; ih < 12; ++ih) {
      ushort4 uv; uv.x = out4[ih][0]; uv.y = out4[ih][1]; uv.z = out4[ih][2]; uv.w = out4[ih][3];
      *(ushort4*)(tile + (ih*32 + kk)*40 + qg) = uv;
    }
    __syncthreads();
#pragma unroll
    for (int rr = 0; rr < 2; ++rr) {
      int row = rr * 256 + t;
      if (row < 384) {
        int ih = row >> 5, kr = row & 31;
        int i = ih >> 2, hh = ih & 3;
        u16* dst = biasT + ((((size_t)i * BB + b) * WW + w) * HH + hh) * 4096 + (size_t)(kc*32 + kr) * 32;
        const u16* srcr = tile + (ih*32 + kr)*40;
        *(uint4*)(dst +  0) = *(const uint4*)(srcr +  0);
        *(uint4*)(dst +  8) = *(const uint4*)(srcr +  8);
        *(uint4*)(dst + 16) = *(const uint4*)(srcr + 16);
        *(uint4*)(dst + 24) = *(const uint4*)(srcr + 24);
      }
    }
  }
}

// ---------------------------------------------------------------------------
// MFMA windowed attention: one WAVE per (w, h, b).  All operand fragments load
// directly from global (Q,K natural [tok][128]; V transposed [b][d][tok]).
// P^T round-trips through 9.2 KB LDS.  Output g-gated bf16.
// ---------------------------------------------------------------------------
__global__ __launch_bounds__(64) void attn_mfma(const u16* __restrict__ Qb,
                                                const u16* __restrict__ Kb,
                                                const u16* __restrict__ Vtb,
                                                const u16* __restrict__ Gb,
                                                const u16* __restrict__ biasT,
                                                u16* __restrict__ Ob) {
  const int w = blockIdx.x, h = blockIdx.y, b = blockIdx.z;
  __shared__ u16 Pt[128 * 36];
  __shared__ float inv_s[32];
  const int lane = threadIdx.x;
  const int l15 = lane & 15, quad = lane >> 4;
  const int tok0 = w * NQW - 48;

  // ---- QK^T:  lg[mt][nt] = Q(32x32) @ K^T(32x128) ----
  short8 qf[2];
#pragma unroll
  for (int mt = 0; mt < 2; ++mt) {
    int qq = w * NQW + mt * 16 + l15;
    qf[mt] = *(const short8*)(Qb + (size_t)(b * NN + qq) * CA + h * DD + quad * 8);
  }
  floatx4 lg[2][8] = {};
#pragma unroll
  for (int nt = 0; nt < 8; ++nt) {
    int tk = tok0 + nt * 16 + l15;
    int tc = min(max(tk, 0), NN - 1);
    short8 kf = *(const short8*)(Kb + (size_t)(b * NN + tc) * CA + h * DD + quad * 8);
#pragma unroll
    for (int mt = 0; mt < 2; ++mt)
      lg[mt][nt] = __builtin_amdgcn_mfma_f32_16x16x32_bf16(qf[mt], kf, lg[mt][nt], 0, 0, 0);
  }

  // ---- scale + bias + mask, row max ----
  const float scale = 0.17677669529663687f;   // 1/sqrt(32)
  const u16* bb = biasT + ((((size_t)b * WW + w) * HH + h) << 12);
  float mrow[2][4];
#pragma unroll
  for (int mt = 0; mt < 2; ++mt)
#pragma unroll
    for (int r = 0; r < 4; ++r) mrow[mt][r] = -3.0e38f;
#pragma unroll
  for (int nt = 0; nt < 8; ++nt) {
    int tk = tok0 + nt * 16 + l15;
    bool valid = (tk >= 0) && (tk < NN);
#pragma unroll
    for (int mt = 0; mt < 2; ++mt) {
      ushort4 bv = *(const ushort4*)(bb + (nt * 16 + l15) * 32 + mt * 16 + quad * 4);
      float bvf[4] = {bf2f(bv.x), bf2f(bv.y), bf2f(bv.z), bf2f(bv.w)};
#pragma unroll
      for (int r = 0; r < 4; ++r) {
        float l = valid ? (lg[mt][nt][r] * scale + bvf[r]) : -1e9f;
        lg[mt][nt][r] = l;
        mrow[mt][r] = fmaxf(mrow[mt][r], l);
      }
    }
  }
#pragma unroll
  for (int mt = 0; mt < 2; ++mt)
#pragma unroll
    for (int r = 0; r < 4; ++r) {
      float m = mrow[mt][r];
      m = fmaxf(m, __shfl_xor(m, 1));
      m = fmaxf(m, __shfl_xor(m, 2));
      m = fmaxf(m, __shfl_xor(m, 4));
      m = fmaxf(m, __shfl_xor(m, 8));
      mrow[mt][r] = m;
    }

  // ---- exp, row sum, write P^T[key][q] ----
  float srow[2][4] = {};
#pragma unroll
  for (int nt = 0; nt < 8; ++nt)
#pragma unroll
    for (int mt = 0; mt < 2; ++mt) {
      u16 pv[4];
#pragma unroll
      for (int r = 0; r < 4; ++r) {
        float e = __expf(lg[mt][nt][r] - mrow[mt][r]);
        srow[mt][r] += e;
        pv[r] = f2bf(e);
      }
      ushort4 uv; uv.x = pv[0]; uv.y = pv[1]; uv.z = pv[2]; uv.w = pv[3];
      *(ushort4*)(Pt + (nt * 16 + l15) * 36 + mt * 16 + quad * 4) = uv;
    }
#pragma unroll
  for (int mt = 0; mt < 2; ++mt)
#pragma unroll
    for (int r = 0; r < 4; ++r) {
      float ssum = srow[mt][r];
      ssum += __shfl_xor(ssum, 1);
      ssum += __shfl_xor(ssum, 2);
      ssum += __shfl_xor(ssum, 4);
      ssum += __shfl_xor(ssum, 8);
      if (l15 == 0) inv_s[mt * 16 + quad * 4 + r] = 1.f / ssum;
    }
  __syncthreads();

  // ---- O^T = V^T @ P^T :  A = V^T (global), B = P^T (LDS) ----
  floatx4 oacc[2][2] = {};
#pragma unroll
  for (int ks = 0; ks < 4; ++ks) {
    short8 pf[2];
#pragma unroll
    for (int ntq = 0; ntq < 2; ++ntq)
#pragma unroll
      for (int j = 0; j < 8; ++j)
        pf[ntq][j] = (short)Pt[(ks * 32 + quad * 8 + j) * 36 + ntq * 16 + l15];
    int tb = tok0 + ks * 32 + quad * 8;
    tb = min(max(tb, 0), NN - 8);
#pragma unroll
    for (int mtd = 0; mtd < 2; ++mtd) {
      short8 vf = *(const short8*)(Vtb + (size_t)(b * CA + h * DD + mtd * 16 + l15) * NN + tb);
#pragma unroll
      for (int ntq = 0; ntq < 2; ++ntq)
        oacc[mtd][ntq] = __builtin_amdgcn_mfma_f32_16x16x32_bf16(vf, pf[ntq], oacc[mtd][ntq], 0, 0, 0);
    }
  }

  // ---- epilogue: O[tok][d] = g * O^T[d][q] / sum ----
#pragma unroll
  for (int mtd = 0; mtd < 2; ++mtd)
#pragma unroll
    for (int ntq = 0; ntq < 2; ++ntq) {
      int qq = ntq * 16 + l15;
      float inv = inv_s[qq];
      int tok = w * NQW + qq;
      size_t base = (size_t)(b * NN + tok) * CA + h * DD + mtd * 16 + quad * 4;
      ushort4 gv = *(const ushort4*)(Gb + base);
      floatx4 v = oacc[mtd][ntq];
      ushort4 o;
      o.x = f2bf(bf2f(gv.x) * v[0] * inv);
      o.y = f2bf(bf2f(gv.y) * v[1] * inv);
      o.z = f2bf(bf2f(gv.z) * v[2] * inv);
      o.w = f2bf(bf2f(gv.w) * v[3] * inv);
      *(ushort4*)(Ob + base) = o;
    }
}

// ---------------------------------------------------------------------------
// Host-side orchestration.
// ---------------------------------------------------------------------------
extern "C" void kernel_launch(void* const* d_in, const int* in_sizes, int n_in,
                              void* d_out, int out_size, void* d_ws, size_t ws_size,
                              hipStream_t stream) {
  const float* q             = (const float*)d_in[0];
  const float* s             = (const float*)d_in[1];
  const float* p             = (const float*)d_in[2];
  const float* adaln_scale_w = (const float*)d_in[3];
  const float* adaln_scale_b = (const float*)d_in[4];
  const float* adaln_shift_w = (const float*)d_in[5];
  const float* wq            = (const float*)d_in[6];
  const float* bq            = (const float*)d_in[7];
  const float* wk            = (const float*)d_in[8];
  const float* wv            = (const float*)d_in[9];
  const float* lnz_w         = (const float*)d_in[10];
  const float* lnz_b         = (const float*)d_in[11];
  const float* wb_pair       = (const float*)d_in[12];
  const float* wg            = (const float*)d_in[13];
  const float* wo            = (const float*)d_in[14];
  const float* sgate_w       = (const float*)d_in[15];
  const float* sgate_b       = (const float*)d_in[16];
  const float* t_scale_w     = (const float*)d_in[17];
  const float* t_scale_b     = (const float*)d_in[18];
  const float* t_shift_w     = (const float*)d_in[19];
  const float* t_wa          = (const float*)d_in[20];
  const float* t_wb          = (const float*)d_in[21];
  const float* t_wo          = (const float*)d_in[22];
  const float* t_sgate_w     = (const float*)d_in[23];
  const float* t_sgate_b     = (const float*)d_in[24];
  float* out = (float*)d_out;

  const size_t MC = (size_t)MR * CA; // 2097152
  float* fws   = (float*)d_ws;
  float* abuf0 = fws;
  float* abuf1 = abuf0 + MC;
  u16* uws     = (u16*)(abuf1 + MC);
  u16* s_ln_bf = uws;                          // MR*CS
  u16* SP      = s_ln_bf + (size_t)MR * CS;    // 6*MC
  u16* amod    = SP + 6*MC;
  u16* tmod    = amod + MC;
  u16* Qb      = tmod + MC;
  u16* Kb      = Qb + MC;
  u16* Vtb     = Kb + MC;                      // [b][128][NN]
  u16* Gb      = Vtb + MC;
  u16* Ob      = Gb + MC;
  u16* HIDb    = Ob + MC;                      // MR*HIDN = 2*MC
  u16* biasT   = HIDb + 2*MC;                  // 3*BB*WW*HH*4096
  u16* wbuf    = biasT + (size_t)3*BB*WW*HH*NQW*NKW;

  const size_t WBLK = 6*(size_t)CA*CS + 5*(size_t)CA*CA + 3*(size_t)CA*HIDN;
  const size_t o_ascale = 0;
  const size_t o_ashift = o_ascale + (size_t)CA*CS;
  const size_t o_sgate  = o_ashift + (size_t)CA*CS;
  const size_t o_tscale = o_sgate  + (size_t)CA*CS;
  const size_t o_tshift = o_tscale + (size_t)CA*CS;
  const size_t o_tsgate = o_tshift + (size_t)CA*CS;
  const size_t o_wq     = o_tsgate + (size_t)CA*CS;
  const size_t o_wk     = o_wq + (size_t)CA*CA;
  const size_t o_wv     = o_wk + (size_t)CA*CA;
  const size_t o_wg     = o_wv + (size_t)CA*CA;
  const size_t o_wo     = o_wg + (size_t)CA*CA;
  const size_t o_twa    = o_wo + (size_t)CA*CA;
  const size_t o_twb    = o_twa + (size_t)HIDN*CA;
  const size_t o_two    = o_twb + (size_t)HIDN*CA;

  // ---- one-time work ----
  ln_s_kernel<<<MR/4, 256, 0, stream>>>(s, s_ln_bf);

  TJobs tj;
  for (int i = 0; i < NBLK; ++i) {
    u16* wb0 = wbuf + (size_t)i * WBLK;
    int b14 = i * 14;
    tj.j[b14+0]  = TJob{adaln_scale_w + (size_t)i*CS*CA, wb0 + o_ascale, CS, CA};
    tj.j[b14+1]  = TJob{adaln_shift_w + (size_t)i*CS*CA, wb0 + o_ashift, CS, CA};
    tj.j[b14+2]  = TJob{sgate_w       + (size_t)i*CS*CA, wb0 + o_sgate,  CS, CA};
    tj.j[b14+3]  = TJob{t_scale_w     + (size_t)i*CS*CA, wb0 + o_tscale, CS, CA};
    tj.j[b14+4]  = TJob{t_shift_w     + (size_t)i*CS*CA, wb0 + o_tshift, CS, CA};
    tj.j[b14+5]  = TJob{t_sgate_w     + (size_t)i*CS*CA, wb0 + o_tsgate, CS, CA};
    tj.j[b14+6]  = TJob{wq   + (size_t)i*CA*CA,   wb0 + o_wq,  CA, CA};
    tj.j[b14+7]  = TJob{wk   + (size_t)i*CA*CA,   wb0 + o_wk,  CA, CA};
    tj.j[b14+8]  = TJob{wv   + (size_t)i*CA*CA,   wb0 + o_wv,  CA, CA};
    tj.j[b14+9]  = TJob{wg   + (size_t)i*CA*CA,   wb0 + o_wg,  CA, CA};
    tj.j[b14+10] = TJob{wo   + (size_t)i*CA*CA,   wb0 + o_wo,  CA, CA};
    tj.j[b14+11] = TJob{t_wa + (size_t)i*CA*HIDN, wb0 + o_twa, CA, HIDN};
    tj.j[b14+12] = TJob{t_wb + (size_t)i*CA*HIDN, wb0 + o_twb, CA, HIDN};
    tj.j[b14+13] = TJob{t_wo + (size_t)i*HIDN*CA, wb0 + o_two, HIDN, CA};
  }
  transpose_bf16<<<dim3(12, 8, 42), 256, 0, stream>>>(tj);

  bias3_kernel<<<dim3(WW, BB), 256, 0, stream>>>(p, lnz_w, lnz_b, wb_pair, biasT);

  for (int i = 0; i < NBLK; ++i) {
    const float* a_in = (i == 0) ? q : (i == 1 ? abuf0 : abuf1);
    float* a_out = (i == 2) ? out : (i == 0 ? abuf0 : abuf1);
    u16* wb0 = wbuf + (size_t)i * WBLK;

    // 6 projections of s_ln (K=384 -> N=128 each), bf16 outs
    GemmJobs js = {};
    js.j[0] = GemmJob{wb0 + o_ascale, nullptr, adaln_scale_b + i*CA, nullptr, nullptr, SP + 0*MC, 1, 0};
    js.j[1] = GemmJob{wb0 + o_ashift, nullptr, nullptr,              nullptr, nullptr, SP + 1*MC, 0, 0};
    js.j[2] = GemmJob{wb0 + o_sgate,  nullptr, sgate_b   + i*CA,     nullptr, nullptr, SP + 2*MC, 1, 0};
    js.j[3] = GemmJob{wb0 + o_tscale, nullptr, t_scale_b + i*CA,     nullptr, nullptr, SP + 3*MC, 1, 0};
    js.j[4] = GemmJob{wb0 + o_tshift, nullptr, nullptr,              nullptr, nullptr, SP + 4*MC, 0, 0};
    js.j[5] = GemmJob{wb0 + o_tsgate, nullptr, t_sgate_b + i*CA,     nullptr, nullptr, SP + 5*MC, 1, 0};
    gemm_mfma<false><<<dim3(1, MR/128, 6), 256, 0, stream>>>(s_ln_bf, CS, CA, js);

    // LN(a) + both modulations -> bf16
    modln_kernel<<<MR/4, 256, 0, stream>>>(a_in, SP + 0*MC, SP + 1*MC, SP + 3*MC, SP + 4*MC,
                                           amod, tmod);

    // Q, K, V(transposed), G projections -> bf16
    GemmJobs jq = {};
    jq.j[0] = GemmJob{wb0 + o_wq, nullptr, bq + i*CA, nullptr, nullptr, Qb,  0, 0};
    jq.j[1] = GemmJob{wb0 + o_wk, nullptr, nullptr,   nullptr, nullptr, Kb,  0, 0};
    jq.j[2] = GemmJob{wb0 + o_wv, nullptr, nullptr,   nullptr, nullptr, Vtb, 5, 0};
    jq.j[3] = GemmJob{wb0 + o_wg, nullptr, nullptr,   nullptr, nullptr, Gb,  1, 0};
    gemm_mfma<false><<<dim3(1, MR/128, 4), 256, 0, stream>>>(amod, CA, CA, jq);

    // windowed attention (MFMA, g-gated bf16 out)
    attn_mfma<<<dim3(WW, HH, BB), 64, 0, stream>>>(
        Qb, Kb, Vtb, Gb, biasT + (size_t)i * BB*WW*HH*4096, Ob);

    // attn_out = (O @ wo) * sgate  -> a_out (fp32)
    GemmJobs ja = {};
    ja.j[0] = GemmJob{wb0 + o_wo, nullptr, nullptr, SP + 2*MC, a_out, nullptr, 2, 0};
    gemm_mfma<false><<<dim3(1, MR/128, 1), 256, 0, stream>>>(Ob, CA, CA, ja);

    // hidden = silu(tmod @ t_wa) * (tmod @ t_wb)  -> bf16 (N=256)
    GemmJobs jh = {};
    jh.j[0] = GemmJob{wb0 + o_twa, wb0 + o_twb, nullptr, nullptr, nullptr, HIDb, 4, 0};
    gemm_mfma<true><<<dim3(2, MR/128, 1), 256, 0, stream>>>(tmod, CA, HIDN, jh);

    // a_out += (hidden @ t_wo) * t_sgate   (K=256)
    GemmJobs jt = {};
    jt.j[0] = GemmJob{wb0 + o_two, nullptr, nullptr, SP + 5*MC, a_out, nullptr, 3, 0};
    gemm_mfma<false><<<dim3(1, MR/128, 1), 256, 0, stream>>>(HIDb, HIDN, CA, jt);
  }
}

// Round 4
// 548.057 us; speedup vs baseline: 3.4742x; 1.2833x over previous
//
#include <hip/hip_runtime.h>
#include <hip/hip_bf16.h>
#include <cstddef>
#include <cstdint>

// Problem constants
#define BB   2
#define NN   8192
#define CA   128
#define CS   384
#define CZ   16
#define HH   4
#define DD   32
#define NQW  32      // NQ
#define NKW  128     // NK
#define NBLK 3
#define WW   256     // N / NQ
#define MR   (BB*NN) // 16384 rows
#define HIDN 256     // 2*CA

typedef unsigned short u16;
typedef __attribute__((ext_vector_type(8))) short short8;
typedef __attribute__((ext_vector_type(4))) float floatx4;

__device__ __forceinline__ float sigmoidf_(float x) { return 1.f / (1.f + __expf(-x)); }

__device__ __forceinline__ u16 f2bf(float x) {
  unsigned u = __float_as_uint(x);
  unsigned r = (u + 0x7fffu + ((u >> 16) & 1u)) >> 16;
  return (u16)r;
}
__device__ __forceinline__ float bf2f(u16 u) {
  return __uint_as_float(((unsigned)u) << 16);
}

// ---------------------------------------------------------------------------
// LayerNorm of s (C_S = 384), one wave per row -> bf16 out.
// ---------------------------------------------------------------------------
__global__ __launch_bounds__(256) void ln_s_kernel(const float* __restrict__ s,
                                                   u16* __restrict__ s_ln_bf) {
  int row  = blockIdx.x * 4 + (threadIdx.x >> 6);
  int lane = threadIdx.x & 63;
  const float* sr = s + (size_t)row * CS;
  float x[6];
  float sum = 0.f, sq = 0.f;
#pragma unroll
  for (int t = 0; t < 6; ++t) { x[t] = sr[lane + 64*t]; sum += x[t]; sq += x[t]*x[t]; }
#pragma unroll
  for (int off = 32; off; off >>= 1) { sum += __shfl_down(sum, off); sq += __shfl_down(sq, off); }
  sum = __shfl(sum, 0); sq = __shfl(sq, 0);
  float mean = sum * (1.f/CS);
  float var  = sq  * (1.f/CS) - mean*mean;
  float rstd = rsqrtf(var + 1e-5f);
  u16* orow = s_ln_bf + (size_t)row * CS;
#pragma unroll
  for (int t = 0; t < 6; ++t) orow[lane + 64*t] = f2bf((x[t]-mean)*rstd);
}

// ---------------------------------------------------------------------------
// LN(a) + adaLN modulation for attention (amod) and transition (tmod), bf16.
// ---------------------------------------------------------------------------
__global__ __launch_bounds__(256) void modln_kernel(const float* __restrict__ a,
                                                    const u16* __restrict__ sp0,
                                                    const u16* __restrict__ sp1,
                                                    const u16* __restrict__ sp3,
                                                    const u16* __restrict__ sp4,
                                                    u16* __restrict__ amod,
                                                    u16* __restrict__ tmod) {
  int row  = blockIdx.x * 4 + (threadIdx.x >> 6);
  int lane = threadIdx.x & 63;
  const float* ar = a + (size_t)row * CA;
  float x0 = ar[lane], x1 = ar[lane + 64];
  float sum = x0 + x1, sq = x0*x0 + x1*x1;
#pragma unroll
  for (int off = 32; off; off >>= 1) { sum += __shfl_down(sum, off); sq += __shfl_down(sq, off); }
  sum = __shfl(sum, 0); sq = __shfl(sq, 0);
  float mean = sum * (1.f/CA);
  float var  = sq  * (1.f/CA) - mean*mean;
  float rstd = rsqrtf(var + 1e-5f);
  float n0 = (x0-mean)*rstd, n1 = (x1-mean)*rstd;
  size_t i0 = (size_t)row * CA + lane;
  amod[i0]      = f2bf(bf2f(sp0[i0])     *n0 + bf2f(sp1[i0]));
  amod[i0 + 64] = f2bf(bf2f(sp0[i0 + 64])*n1 + bf2f(sp1[i0 + 64]));
  tmod[i0]      = f2bf(bf2f(sp3[i0])     *n0 + bf2f(sp4[i0]));
  tmod[i0 + 64] = f2bf(bf2f(sp3[i0 + 64])*n1 + bf2f(sp4[i0 + 64]));
}

// ---------------------------------------------------------------------------
// Weight transpose+convert: src fp32 K x N (row-major)  ->  dst bf16 N x K.
// ---------------------------------------------------------------------------
struct TJob { const float* src; u16* dst; int K; int N; };
struct TJobs { TJob j[42]; };

__global__ __launch_bounds__(256) void transpose_bf16(TJobs jobs) {
  TJob jb = jobs.j[blockIdx.z];
  int tk = blockIdx.x * 32, tn = blockIdx.y * 32;
  if (tk >= jb.K || tn >= jb.N) return;
  __shared__ float tile[32][33];
  int tx = threadIdx.x & 31;
  int ty = threadIdx.x >> 5;
#pragma unroll
  for (int r = ty; r < 32; r += 8) tile[r][tx] = jb.src[(size_t)(tk + r) * jb.N + tn + tx];
  __syncthreads();
#pragma unroll
  for (int r = ty; r < 32; r += 8)
    jb.dst[(size_t)(tn + r) * jb.K + tk + tx] = f2bf(tile[tx][r]);
}

// ---------------------------------------------------------------------------
// bf16 MFMA GEMM.  128x128 block tile, BK=32, 4 waves (2x2 of 64x64).
// Per-job A pointer + K.  modes: 0 = (+bias)->bf16, 1 = sigmoid(+bias)->bf16,
// 4 (DUAL) = silu(A@B)*(A@B2) -> bf16, 5 = transposed bf16 write (V).
// ---------------------------------------------------------------------------
struct GemmJob {
  const u16* A;
  const u16* Bt;
  const u16* Bt2;
  const float* bias;
  u16* outbf;
  int K;
  int ostride;
  int mode;
  int pad;
};
struct GemmJobs { GemmJob j[18]; };

#define CH_STRIDE 1032   // ushorts per k-chunk plane (128*8 + 8 pad)

template <bool DUAL>
__global__ __launch_bounds__(256) void gemm_mfma(GemmJobs jobs) {
  GemmJob jb = jobs.j[blockIdx.z];
  const int bm = blockIdx.y * 128, bn = blockIdx.x * 128;
  const int K = jb.K;

  __shared__ u16 As[4 * CH_STRIDE];
  __shared__ u16 Bs[4 * CH_STRIDE];
  __shared__ u16 Bs2[DUAL ? 4 * CH_STRIDE : 8];

  const int tid  = threadIdx.x;
  const int lane = tid & 63;
  const int wave = tid >> 6;
  const int wr = wave >> 1, wc = wave & 1;
  const int l15 = lane & 15, quad = lane >> 4;

  floatx4 acc[4][4] = {};
  floatx4 acc2[DUAL ? 4 : 1][DUAL ? 4 : 1] = {};

  for (int k0 = 0; k0 < K; k0 += 32) {
    __syncthreads();
#pragma unroll
    for (int h = 0; h < 2; ++h) {
      int f = tid + 256 * h;
      int m = f >> 2, c = f & 3;
      uint4 av = *(const uint4*)(jb.A + (size_t)(bm + m) * K + k0 + c * 8);
      *(uint4*)(As + c * CH_STRIDE + m * 8) = av;
      uint4 bv = *(const uint4*)(jb.Bt + (size_t)(bn + m) * K + k0 + c * 8);
      *(uint4*)(Bs + c * CH_STRIDE + m * 8) = bv;
      if constexpr (DUAL) {
        uint4 bv2 = *(const uint4*)(jb.Bt2 + (size_t)(bn + m) * K + k0 + c * 8);
        *(uint4*)(Bs2 + c * CH_STRIDE + m * 8) = bv2;
      }
    }
    __syncthreads();

    short8 a_frag[4], b_frag[4];
#pragma unroll
    for (int mt = 0; mt < 4; ++mt)
      a_frag[mt] = *(const short8*)(As + quad * CH_STRIDE + (wr * 64 + mt * 16 + l15) * 8);
#pragma unroll
    for (int nt = 0; nt < 4; ++nt)
      b_frag[nt] = *(const short8*)(Bs + quad * CH_STRIDE + (wc * 64 + nt * 16 + l15) * 8);
#pragma unroll
    for (int mt = 0; mt < 4; ++mt)
#pragma unroll
      for (int nt = 0; nt < 4; ++nt)
        acc[mt][nt] = __builtin_amdgcn_mfma_f32_16x16x32_bf16(a_frag[mt], b_frag[nt], acc[mt][nt], 0, 0, 0);
    if constexpr (DUAL) {
      short8 b2_frag[4];
#pragma unroll
      for (int nt = 0; nt < 4; ++nt)
        b2_frag[nt] = *(const short8*)(Bs2 + quad * CH_STRIDE + (wc * 64 + nt * 16 + l15) * 8);
#pragma unroll
      for (int mt = 0; mt < 4; ++mt)
#pragma unroll
        for (int nt = 0; nt < 4; ++nt)
          acc2[mt][nt] = __builtin_amdgcn_mfma_f32_16x16x32_bf16(a_frag[mt], b2_frag[nt], acc2[mt][nt], 0, 0, 0);
    }
  }

  // Epilogue.  C/D layout: col = lane&15, row = quad*4 + reg.
#pragma unroll
  for (int mt = 0; mt < 4; ++mt) {
#pragma unroll
    for (int nt = 0; nt < 4; ++nt) {
      int n = bn + wc * 64 + nt * 16 + l15;
      int mbase = bm + wr * 64 + mt * 16 + quad * 4;
      floatx4 v = acc[mt][nt];
      if constexpr (DUAL) {
        floatx4 v2 = acc2[mt][nt];
#pragma unroll
        for (int r = 0; r < 4; ++r) {
          size_t idx = (size_t)(mbase + r) * jb.ostride + n;
          float x1 = v[r];
          jb.outbf[idx] = f2bf(x1 * sigmoidf_(x1) * v2[r]);
        }
      } else if (jb.mode == 5) {
        int bidx = mbase >> 13;          // m / NN
        int tok  = mbase & (NN - 1);
        ushort4 o;
        o.x = f2bf(v[0]); o.y = f2bf(v[1]); o.z = f2bf(v[2]); o.w = f2bf(v[3]);
        *(ushort4*)(jb.outbf + (size_t)(bidx * CA + n) * NN + tok) = o;
      } else {
        float bias = jb.bias ? jb.bias[n] : 0.f;
#pragma unroll
        for (int r = 0; r < 4; ++r) {
          size_t idx = (size_t)(mbase + r) * jb.ostride + n;
          float x = v[r] + bias;
          jb.outbf[idx] = f2bf(jb.mode == 1 ? sigmoidf_(x) : x);
        }
      }
    }
  }
}

// ---------------------------------------------------------------------------
// Combo output kernel: out = (O @ woT)*g1 + (HID @ twoT)*g2, fp32.
// Two K-loops sharing LDS; grid (1, MR/128).
// ---------------------------------------------------------------------------
__global__ __launch_bounds__(256) void combo_kernel(const u16* __restrict__ O,
                                                    const u16* __restrict__ HID,
                                                    const u16* __restrict__ woT,
                                                    const u16* __restrict__ twoT,
                                                    const u16* __restrict__ g1,
                                                    const u16* __restrict__ g2,
                                                    float* __restrict__ outp) {
  const int bm = blockIdx.y * 128;
  __shared__ u16 As[4 * CH_STRIDE];
  __shared__ u16 Bs[4 * CH_STRIDE];
  const int tid  = threadIdx.x;
  const int lane = tid & 63;
  const int wave = tid >> 6;
  const int wr = wave >> 1, wc = wave & 1;
  const int l15 = lane & 15, quad = lane >> 4;

  floatx4 acc1[4][4] = {};
  floatx4 acc2[4][4] = {};

  // pass 1: K=128 over O/woT
  for (int k0 = 0; k0 < CA; k0 += 32) {
    __syncthreads();
#pragma unroll
    for (int h = 0; h < 2; ++h) {
      int f = tid + 256 * h;
      int m = f >> 2, c = f & 3;
      *(uint4*)(As + c * CH_STRIDE + m * 8) = *(const uint4*)(O + (size_t)(bm + m) * CA + k0 + c * 8);
      *(uint4*)(Bs + c * CH_STRIDE + m * 8) = *(const uint4*)(woT + (size_t)m * CA + k0 + c * 8);
    }
    __syncthreads();
    short8 a_frag[4], b_frag[4];
#pragma unroll
    for (int mt = 0; mt < 4; ++mt)
      a_frag[mt] = *(const short8*)(As + quad * CH_STRIDE + (wr * 64 + mt * 16 + l15) * 8);
#pragma unroll
    for (int nt = 0; nt < 4; ++nt)
      b_frag[nt] = *(const short8*)(Bs + quad * CH_STRIDE + (wc * 64 + nt * 16 + l15) * 8);
#pragma unroll
    for (int mt = 0; mt < 4; ++mt)
#pragma unroll
      for (int nt = 0; nt < 4; ++nt)
        acc1[mt][nt] = __builtin_amdgcn_mfma_f32_16x16x32_bf16(a_frag[mt], b_frag[nt], acc1[mt][nt], 0, 0, 0);
  }
  // pass 2: K=256 over HID/twoT
  for (int k0 = 0; k0 < HIDN; k0 += 32) {
    __syncthreads();
#pragma unroll
    for (int h = 0; h < 2; ++h) {
      int f = tid + 256 * h;
      int m = f >> 2, c = f & 3;
      *(uint4*)(As + c * CH_STRIDE + m * 8) = *(const uint4*)(HID + (size_t)(bm + m) * HIDN + k0 + c * 8);
      *(uint4*)(Bs + c * CH_STRIDE + m * 8) = *(const uint4*)(twoT + (size_t)m * HIDN + k0 + c * 8);
    }
    __syncthreads();
    short8 a_frag[4], b_frag[4];
#pragma unroll
    for (int mt = 0; mt < 4; ++mt)
      a_frag[mt] = *(const short8*)(As + quad * CH_STRIDE + (wr * 64 + mt * 16 + l15) * 8);
#pragma unroll
    for (int nt = 0; nt < 4; ++nt)
      b_frag[nt] = *(const short8*)(Bs + quad * CH_STRIDE + (wc * 64 + nt * 16 + l15) * 8);
#pragma unroll
    for (int mt = 0; mt < 4; ++mt)
#pragma unroll
      for (int nt = 0; nt < 4; ++nt)
        acc2[mt][nt] = __builtin_amdgcn_mfma_f32_16x16x32_bf16(a_frag[mt], b_frag[nt], acc2[mt][nt], 0, 0, 0);
  }

#pragma unroll
  for (int mt = 0; mt < 4; ++mt) {
#pragma unroll
    for (int nt = 0; nt < 4; ++nt) {
      int n = wc * 64 + nt * 16 + l15;
      int mbase = bm + wr * 64 + mt * 16 + quad * 4;
#pragma unroll
      for (int r = 0; r < 4; ++r) {
        size_t idx = (size_t)(mbase + r) * CA + n;
        outp[idx] = acc1[mt][nt][r] * bf2f(g1[idx]) + acc2[mt][nt][r] * bf2f(g2[idx]);
      }
    }
  }
}

// ---------------------------------------------------------------------------
// Pair bias for ALL 3 blocks in one pass over p; no LDS transpose, direct
// ushort4 stores.  Grid (4 k-chunks, W, B).
// Output layout: biasT[i][b][w][h][k][q] (bf16).
// ---------------------------------------------------------------------------
__global__ __launch_bounds__(256) void bias3_kernel(const float* __restrict__ p,
                                                    const float* __restrict__ lnz_w,
                                                    const float* __restrict__ lnz_b,
                                                    const float* __restrict__ wb,
                                                    u16* __restrict__ biasT) {
  const int kc = blockIdx.x, w = blockIdx.y, b = blockIdx.z;
  __shared__ float effW[12][16];
  __shared__ float effb[12];
  const int t = threadIdx.x;
  if (t < 192) {
    int i = t >> 6, rem = t & 63, z = rem >> 2, hh = rem & 3;
    effW[i*4 + hh][z] = lnz_w[i*CZ + z] * wb[(i*CZ + z)*HH + hh];
  }
  if (t < 12) {
    int i = t >> 2, hh = t & 3;
    float acc = 0.f;
    for (int z = 0; z < 16; ++z) acc += lnz_b[i*CZ + z] * wb[(i*CZ + z)*HH + hh];
    effb[t] = acc;
  }
  __syncthreads();

  const int kk = t & 31, qg = (t >> 5) * 4;
  const int k = kc * 32 + kk;
  u16 out4[12][4];
#pragma unroll
  for (int r = 0; r < 4; ++r) {
    int qq = qg + r;
    const float4* pr = (const float4*)(p + (size_t)(((b * WW + w) * NQW + qq) * NKW + k) * 16);
    float4 p0 = pr[0], p1 = pr[1], p2 = pr[2], p3 = pr[3];
    float x[16] = {p0.x,p0.y,p0.z,p0.w, p1.x,p1.y,p1.z,p1.w,
                   p2.x,p2.y,p2.z,p2.w, p3.x,p3.y,p3.z,p3.w};
    float sum = 0.f, sq = 0.f;
#pragma unroll
    for (int z = 0; z < 16; ++z) { sum += x[z]; sq += x[z]*x[z]; }
    float mean = sum * (1.f/16.f);
    float var  = sq  * (1.f/16.f) - mean*mean;
    float rstd = rsqrtf(var + 1e-5f);
#pragma unroll
    for (int ih = 0; ih < 12; ++ih) {
      float acc = effb[ih];
#pragma unroll
      for (int z = 0; z < 16; ++z) acc += (x[z]-mean)*rstd * effW[ih][z];
      out4[ih][r] = f2bf(acc);
    }
  }
#pragma unroll
  for (int ih = 0; ih < 12; ++ih) {
    int i = ih >> 2, hh = ih & 3;
    u16* dst = biasT + ((((size_t)i * BB + b) * WW + w) * HH + hh) * 4096 + (size_t)k * 32 + qg;
    ushort4 uv; uv.x = out4[ih][0]; uv.y = out4[ih][1]; uv.z = out4[ih][2]; uv.w = out4[ih][3];
    *(ushort4*)dst = uv;
  }
}

// ---------------------------------------------------------------------------
// MFMA windowed attention: one WAVE per (w, h, b).
// ---------------------------------------------------------------------------
__global__ __launch_bounds__(64) void attn_mfma(const u16* __restrict__ Qb,
                                                const u16* __restrict__ Kb,
                                                const u16* __restrict__ Vtb,
                                                const u16* __restrict__ Gb,
                                                const u16* __restrict__ biasT,
                                                u16* __restrict__ Ob) {
  const int w = blockIdx.x, h = blockIdx.y, b = blockIdx.z;
  __shared__ u16 Pt[128 * 36];
  __shared__ float inv_s[32];
  const int lane = threadIdx.x;
  const int l15 = lane & 15, quad = lane >> 4;
  const int tok0 = w * NQW - 48;

  short8 qf[2];
#pragma unroll
  for (int mt = 0; mt < 2; ++mt) {
    int qq = w * NQW + mt * 16 + l15;
    qf[mt] = *(const short8*)(Qb + (size_t)(b * NN + qq) * CA + h * DD + quad * 8);
  }
  floatx4 lg[2][8] = {};
#pragma unroll
  for (int nt = 0; nt < 8; ++nt) {
    int tk = tok0 + nt * 16 + l15;
    int tc = min(max(tk, 0), NN - 1);
    short8 kf = *(const short8*)(Kb + (size_t)(b * NN + tc) * CA + h * DD + quad * 8);
#pragma unroll
    for (int mt = 0; mt < 2; ++mt)
      lg[mt][nt] = __builtin_amdgcn_mfma_f32_16x16x32_bf16(qf[mt], kf, lg[mt][nt], 0, 0, 0);
  }

  const float scale = 0.17677669529663687f;   // 1/sqrt(32)
  const u16* bb = biasT + ((((size_t)b * WW + w) * HH + h) << 12);
  float mrow[2][4];
#pragma unroll
  for (int mt = 0; mt < 2; ++mt)
#pragma unroll
    for (int r = 0; r < 4; ++r) mrow[mt][r] = -3.0e38f;
#pragma unroll
  for (int nt = 0; nt < 8; ++nt) {
    int tk = tok0 + nt * 16 + l15;
    bool valid = (tk >= 0) && (tk < NN);
#pragma unroll
    for (int mt = 0; mt < 2; ++mt) {
      ushort4 bv = *(const ushort4*)(bb + (nt * 16 + l15) * 32 + mt * 16 + quad * 4);
      float bvf[4] = {bf2f(bv.x), bf2f(bv.y), bf2f(bv.z), bf2f(bv.w)};
#pragma unroll
      for (int r = 0; r < 4; ++r) {
        float l = valid ? (lg[mt][nt][r] * scale + bvf[r]) : -1e9f;
        lg[mt][nt][r] = l;
        mrow[mt][r] = fmaxf(mrow[mt][r], l);
      }
    }
  }
#pragma unroll
  for (int mt = 0; mt < 2; ++mt)
#pragma unroll
    for (int r = 0; r < 4; ++r) {
      float m = mrow[mt][r];
      m = fmaxf(m, __shfl_xor(m, 1));
      m = fmaxf(m, __shfl_xor(m, 2));
      m = fmaxf(m, __shfl_xor(m, 4));
      m = fmaxf(m, __shfl_xor(m, 8));
      mrow[mt][r] = m;
    }

  float srow[2][4] = {};
#pragma unroll
  for (int nt = 0; nt < 8; ++nt)
#pragma unroll
    for (int mt = 0; mt < 2; ++mt) {
      u16 pv[4];
#pragma unroll
      for (int r = 0; r < 4; ++r) {
        float e = __expf(lg[mt][nt][r] - mrow[mt][r]);
        srow[mt][r] += e;
        pv[r] = f2bf(e);
      }
      ushort4 uv; uv.x = pv[0]; uv.y = pv[1]; uv.z = pv[2]; uv.w = pv[3];
      *(ushort4*)(Pt + (nt * 16 + l15) * 36 + mt * 16 + quad * 4) = uv;
    }
#pragma unroll
  for (int mt = 0; mt < 2; ++mt)
#pragma unroll
    for (int r = 0; r < 4; ++r) {
      float ssum = srow[mt][r];
      ssum += __shfl_xor(ssum, 1);
      ssum += __shfl_xor(ssum, 2);
      ssum += __shfl_xor(ssum, 4);
      ssum += __shfl_xor(ssum, 8);
      if (l15 == 0) inv_s[mt * 16 + quad * 4 + r] = 1.f / ssum;
    }
  __syncthreads();

  floatx4 oacc[2][2] = {};
#pragma unroll
  for (int ks = 0; ks < 4; ++ks) {
    short8 pf[2];
#pragma unroll
    for (int ntq = 0; ntq < 2; ++ntq)
#pragma unroll
      for (int j = 0; j < 8; ++j)
        pf[ntq][j] = (short)Pt[(ks * 32 + quad * 8 + j) * 36 + ntq * 16 + l15];
    int tb = tok0 + ks * 32 + quad * 8;
    tb = min(max(tb, 0), NN - 8);
#pragma unroll
    for (int mtd = 0; mtd < 2; ++mtd) {
      short8 vf = *(const short8*)(Vtb + (size_t)(b * CA + h * DD + mtd * 16 + l15) * NN + tb);
#pragma unroll
      for (int ntq = 0; ntq < 2; ++ntq)
        oacc[mtd][ntq] = __builtin_amdgcn_mfma_f32_16x16x32_bf16(vf, pf[ntq], oacc[mtd][ntq], 0, 0, 0);
    }
  }

#pragma unroll
  for (int mtd = 0; mtd < 2; ++mtd)
#pragma unroll
    for (int ntq = 0; ntq < 2; ++ntq) {
      int qq = ntq * 16 + l15;
      float inv = inv_s[qq];
      int tok = w * NQW + qq;
      size_t base = (size_t)(b * NN + tok) * CA + h * DD + mtd * 16 + quad * 4;
      ushort4 gv = *(const ushort4*)(Gb + base);
      floatx4 v = oacc[mtd][ntq];
      ushort4 o;
      o.x = f2bf(bf2f(gv.x) * v[0] * inv);
      o.y = f2bf(bf2f(gv.y) * v[1] * inv);
      o.z = f2bf(bf2f(gv.z) * v[2] * inv);
      o.w = f2bf(bf2f(gv.w) * v[3] * inv);
      *(ushort4*)(Ob + base) = o;
    }
}

// ---------------------------------------------------------------------------
// Host-side orchestration.
// ---------------------------------------------------------------------------
extern "C" void kernel_launch(void* const* d_in, const int* in_sizes, int n_in,
                              void* d_out, int out_size, void* d_ws, size_t ws_size,
                              hipStream_t stream) {
  const float* q             = (const float*)d_in[0];
  const float* s             = (const float*)d_in[1];
  const float* p             = (const float*)d_in[2];
  const float* adaln_scale_w = (const float*)d_in[3];
  const float* adaln_scale_b = (const float*)d_in[4];
  const float* adaln_shift_w = (const float*)d_in[5];
  const float* wq            = (const float*)d_in[6];
  const float* bq            = (const float*)d_in[7];
  const float* wk            = (const float*)d_in[8];
  const float* wv            = (const float*)d_in[9];
  const float* lnz_w         = (const float*)d_in[10];
  const float* lnz_b         = (const float*)d_in[11];
  const float* wb_pair       = (const float*)d_in[12];
  const float* wg            = (const float*)d_in[13];
  const float* wo            = (const float*)d_in[14];
  const float* sgate_w       = (const float*)d_in[15];
  const float* sgate_b       = (const float*)d_in[16];
  const float* t_scale_w     = (const float*)d_in[17];
  const float* t_scale_b     = (const float*)d_in[18];
  const float* t_shift_w     = (const float*)d_in[19];
  const float* t_wa          = (const float*)d_in[20];
  const float* t_wb          = (const float*)d_in[21];
  const float* t_wo          = (const float*)d_in[22];
  const float* t_sgate_w     = (const float*)d_in[23];
  const float* t_sgate_b     = (const float*)d_in[24];
  float* out = (float*)d_out;

  const size_t MC = (size_t)MR * CA; // 2097152
  float* fws   = (float*)d_ws;
  float* abuf0 = fws;
  float* abuf1 = abuf0 + MC;
  u16* uws     = (u16*)(abuf1 + MC);
  u16* s_ln_bf = uws;                          // MR*CS
  u16* SP      = s_ln_bf + (size_t)MR * CS;    // 18*MC
  u16* amod    = SP + 18*MC;
  u16* tmod    = amod + MC;
  u16* Qb      = tmod + MC;
  u16* Kb      = Qb + MC;
  u16* Vtb     = Kb + MC;                      // [b][128][NN]
  u16* Gb      = Vtb + MC;
  u16* Ob      = Gb + MC;
  u16* HIDb    = Ob + MC;                      // MR*HIDN = 2*MC
  u16* biasT   = HIDb + 2*MC;                  // 3*BB*WW*HH*4096
  u16* wbuf    = biasT + (size_t)3*BB*WW*HH*NQW*NKW;

  const size_t WBLK = 6*(size_t)CA*CS + 5*(size_t)CA*CA + 3*(size_t)CA*HIDN;
  const size_t o_ascale = 0;
  const size_t o_ashift = o_ascale + (size_t)CA*CS;
  const size_t o_sgate  = o_ashift + (size_t)CA*CS;
  const size_t o_tscale = o_sgate  + (size_t)CA*CS;
  const size_t o_tshift = o_tscale + (size_t)CA*CS;
  const size_t o_tsgate = o_tshift + (size_t)CA*CS;
  const size_t o_wq     = o_tsgate + (size_t)CA*CS;
  const size_t o_wk     = o_wq + (size_t)CA*CA;
  const size_t o_wv     = o_wk + (size_t)CA*CA;
  const size_t o_wg     = o_wv + (size_t)CA*CA;
  const size_t o_wo     = o_wg + (size_t)CA*CA;
  const size_t o_twa    = o_wo + (size_t)CA*CA;
  const size_t o_twb    = o_twa + (size_t)HIDN*CA;
  const size_t o_two    = o_twb + (size_t)HIDN*CA;

  // ---- one-time work ----
  ln_s_kernel<<<MR/4, 256, 0, stream>>>(s, s_ln_bf);

  TJobs tj;
  for (int i = 0; i < NBLK; ++i) {
    u16* wb0 = wbuf + (size_t)i * WBLK;
    int b14 = i * 14;
    tj.j[b14+0]  = TJob{adaln_scale_w + (size_t)i*CS*CA, wb0 + o_ascale, CS, CA};
    tj.j[b14+1]  = TJob{adaln_shift_w + (size_t)i*CS*CA, wb0 + o_ashift, CS, CA};
    tj.j[b14+2]  = TJob{sgate_w       + (size_t)i*CS*CA, wb0 + o_sgate,  CS, CA};
    tj.j[b14+3]  = TJob{t_scale_w     + (size_t)i*CS*CA, wb0 + o_tscale, CS, CA};
    tj.j[b14+4]  = TJob{t_shift_w     + (size_t)i*CS*CA, wb0 + o_tshift, CS, CA};
    tj.j[b14+5]  = TJob{t_sgate_w     + (size_t)i*CS*CA, wb0 + o_tsgate, CS, CA};
    tj.j[b14+6]  = TJob{wq   + (size_t)i*CA*CA,   wb0 + o_wq,  CA, CA};
    tj.j[b14+7]  = TJob{wk   + (size_t)i*CA*CA,   wb0 + o_wk,  CA, CA};
    tj.j[b14+8]  = TJob{wv   + (size_t)i*CA*CA,   wb0 + o_wv,  CA, CA};
    tj.j[b14+9]  = TJob{wg   + (size_t)i*CA*CA,   wb0 + o_wg,  CA, CA};
    tj.j[b14+10] = TJob{wo   + (size_t)i*CA*CA,   wb0 + o_wo,  CA, CA};
    tj.j[b14+11] = TJob{t_wa + (size_t)i*CA*HIDN, wb0 + o_twa, CA, HIDN};
    tj.j[b14+12] = TJob{t_wb + (size_t)i*CA*HIDN, wb0 + o_twb, CA, HIDN};
    tj.j[b14+13] = TJob{t_wo + (size_t)i*HIDN*CA, wb0 + o_two, HIDN, CA};
  }
  transpose_bf16<<<dim3(12, 8, 42), 256, 0, stream>>>(tj);

  bias3_kernel<<<dim3(4, WW, BB), 256, 0, stream>>>(p, lnz_w, lnz_b, wb_pair, biasT);

  // ALL 18 s_ln projections (iteration-invariant) in one launch
  {
    GemmJobs js = {};
    for (int i = 0; i < NBLK; ++i) {
      u16* wb0 = wbuf + (size_t)i * WBLK;
      js.j[i*6+0] = GemmJob{s_ln_bf, wb0 + o_ascale, nullptr, adaln_scale_b + i*CA, SP + (i*6+0)*MC, CS, CA, 1, 0};
      js.j[i*6+1] = GemmJob{s_ln_bf, wb0 + o_ashift, nullptr, nullptr,              SP + (i*6+1)*MC, CS, CA, 0, 0};
      js.j[i*6+2] = GemmJob{s_ln_bf, wb0 + o_sgate,  nullptr, sgate_b   + i*CA,     SP + (i*6+2)*MC, CS, CA, 1, 0};
      js.j[i*6+3] = GemmJob{s_ln_bf, wb0 + o_tscale, nullptr, t_scale_b + i*CA,     SP + (i*6+3)*MC, CS, CA, 1, 0};
      js.j[i*6+4] = GemmJob{s_ln_bf, wb0 + o_tshift, nullptr, nullptr,              SP + (i*6+4)*MC, CS, CA, 0, 0};
      js.j[i*6+5] = GemmJob{s_ln_bf, wb0 + o_tsgate, nullptr, t_sgate_b + i*CA,     SP + (i*6+5)*MC, CS, CA, 1, 0};
    }
    gemm_mfma<false><<<dim3(1, MR/128, 18), 256, 0, stream>>>(js);
  }

  for (int i = 0; i < NBLK; ++i) {
    const float* a_in = (i == 0) ? q : (i == 1 ? abuf0 : abuf1);
    float* a_out = (i == 2) ? out : (i == 0 ? abuf0 : abuf1);
    u16* wb0 = wbuf + (size_t)i * WBLK;

    // LN(a) + both modulations -> bf16
    modln_kernel<<<MR/4, 256, 0, stream>>>(a_in, SP + (i*6+0)*MC, SP + (i*6+1)*MC,
                                           SP + (i*6+3)*MC, SP + (i*6+4)*MC, amod, tmod);

    // Q, K, V(transposed), G projections -> bf16
    GemmJobs jq = {};
    jq.j[0] = GemmJob{amod, wb0 + o_wq, nullptr, bq + i*CA, Qb,  CA, CA, 0, 0};
    jq.j[1] = GemmJob{amod, wb0 + o_wk, nullptr, nullptr,   Kb,  CA, CA, 0, 0};
    jq.j[2] = GemmJob{amod, wb0 + o_wv, nullptr, nullptr,   Vtb, CA, CA, 5, 0};
    jq.j[3] = GemmJob{amod, wb0 + o_wg, nullptr, nullptr,   Gb,  CA, CA, 1, 0};
    gemm_mfma<false><<<dim3(1, MR/128, 4), 256, 0, stream>>>(jq);

    // hidden = silu(tmod @ t_wa) * (tmod @ t_wb)  -> bf16 (N=256)
    GemmJobs jh = {};
    jh.j[0] = GemmJob{tmod, wb0 + o_twa, wb0 + o_twb, nullptr, HIDb, CA, HIDN, 4, 0};
    gemm_mfma<true><<<dim3(2, MR/128, 1), 256, 0, stream>>>(jh);

    // windowed attention (MFMA, g-gated bf16 out)
    attn_mfma<<<dim3(WW, HH, BB), 64, 0, stream>>>(
        Qb, Kb, Vtb, Gb, biasT + (size_t)i * BB*WW*HH*4096, Ob);

    // a_out = (O @ wo)*sgate + (HID @ two)*tsgate
    combo_kernel<<<dim3(1, MR/128), 256, 0, stream>>>(
        Ob, HIDb, wb0 + o_wo, wb0 + o_two,
        SP + (i*6+2)*MC, SP + (i*6+5)*MC, a_out);
  }
}